// Round 1
// baseline (168.414 us; speedup 1.0000x reference)
//
#include <hip/hip_runtime.h>

#define EMB   768
#define SEQ   1024
#define NBAT  4
#define MROWS 4096      // NBAT*SEQ
#define NHEAD 12
#define HD    64
#define WIN   16
#define MAXW  33        // 2*WIN+1
#define LN_EPS 1e-5f

typedef __attribute__((ext_vector_type(8))) short bf16x8;
typedef __attribute__((ext_vector_type(4))) float f32x4;
typedef unsigned short u16;
typedef unsigned int   u32;

// ---------------- cast f32 -> bf16 (RNE) ----------------
static __device__ inline u16 f2bf(float f) {
    union { float f; u32 u; } a; a.f = f;
    u32 u = a.u;
    u32 r = (u + 0x7fffu + ((u >> 16) & 1u)) >> 16;
    return (u16)r;
}

// activations: 3 arrays of 4096*768 f32; weights: 3 arrays of 768*768 f32
#define ACT4 786432u    // 4096*768/4
#define WT4  147456u    // 768*768/4
__global__ __launch_bounds__(256) void cast_all(
    const float* __restrict__ q, const float* __restrict__ k, const float* __restrict__ v,
    const float* __restrict__ wq, const float* __restrict__ wk, const float* __restrict__ wv,
    u16* __restrict__ Abf, u16* __restrict__ Wbf)
{
    u32 u = blockIdx.x * 256u + threadIdx.x;
    const float* src; u16* dst; u32 off;
    if (u < 3u * ACT4) {
        u32 which = u / ACT4;
        off = (u - which * ACT4) * 4u;
        src = which == 0 ? q : (which == 1 ? k : v);
        dst = Abf + (size_t)which * 3145728u + off;
    } else {
        u32 w2 = u - 3u * ACT4;
        u32 which = w2 / WT4;
        off = (w2 - which * WT4) * 4u;
        src = which == 0 ? wq : (which == 1 ? wk : wv);
        dst = Wbf + (size_t)which * 589824u + off;
    }
    float4 val = *(const float4*)(src + off);
    ushort4 o;
    o.x = f2bf(val.x); o.y = f2bf(val.y); o.z = f2bf(val.z); o.w = f2bf(val.w);
    *(ushort4*)dst = o;
}

// ---------------- bf16 MFMA GEMM: C[m][n] = sum_k A[m][k]*W[n][k] + bias[n] ----------------
// m97-style: 128x128 tile, BK=32, 4 waves (2x2 of 64x64), global_load_lds width 16.
#define GK 768
#define GN 768

static __device__ inline void gload_lds16(const void* g, void* l) {
    __builtin_amdgcn_global_load_lds((const __attribute__((address_space(1))) void*)g,
                                     (__attribute__((address_space(3))) void*)l, 16, 0, 0);
}

__global__ __launch_bounds__(256) void gemm_qkv(
    const u16* __restrict__ Abase, const u16* __restrict__ Wbase,
    const float* __restrict__ bq, const float* __restrict__ bk, const float* __restrict__ bv,
    float* __restrict__ Obase)
{
    const int z = blockIdx.z;
    const u16* A = Abase + (size_t)z * (MROWS * GK);
    const u16* W = Wbase + (size_t)z * (GN * GK);
    const float* bias = (z == 0) ? bq : ((z == 1) ? bk : bv);
    float* O = Obase + (size_t)z * (MROWS * GN);

    const int bm = blockIdx.y * 128, bn = blockIdx.x * 128;
    const int tid = threadIdx.x, wave = tid >> 6, lane = tid & 63;

    __shared__ __align__(16) u16 As[128 * 32];
    __shared__ __align__(16) u16 Bs[128 * 32];

    f32x4 acc[4][4];
#pragma unroll
    for (int i = 0; i < 4; ++i)
#pragma unroll
        for (int j = 0; j < 4; ++j) acc[i][j] = (f32x4){0.f, 0.f, 0.f, 0.f};

    const int wr = (wave >> 1) * 64, wc = (wave & 1) * 64;
    const int r0 = lane & 15, kof = (lane >> 4) * 8;

    for (int k0 = 0; k0 < GK; k0 += 32) {
        // stage A and B tiles: 512 chunks of 16B each, linear LDS, per-wave uniform base
#pragma unroll
        for (int j = 0; j < 2; ++j) {
            int c = (j * 4 + wave) * 64 + lane;        // 0..511
            int row = c >> 2, col = (c & 3) * 8;
            gload_lds16(A + (size_t)(bm + row) * GK + k0 + col, As + (j * 4 + wave) * 512);
            gload_lds16(W + (size_t)(bn + row) * GK + k0 + col, Bs + (j * 4 + wave) * 512);
        }
        __syncthreads();

        bf16x8 af[4], bf[4];
#pragma unroll
        for (int f = 0; f < 4; ++f) {
            af[f] = *(const bf16x8*)&As[(wr + f * 16 + r0) * 32 + kof];
            bf[f] = *(const bf16x8*)&Bs[(wc + f * 16 + r0) * 32 + kof];
        }
#pragma unroll
        for (int i = 0; i < 4; ++i)
#pragma unroll
            for (int j = 0; j < 4; ++j)
                acc[i][j] = __builtin_amdgcn_mfma_f32_16x16x32_bf16(af[i], bf[j], acc[i][j], 0, 0, 0);
        __syncthreads();
    }

    // epilogue: C/D layout col=lane&15, row=(lane>>4)*4+reg
    const int cl = lane & 15, rb = (lane >> 4) * 4;
#pragma unroll
    for (int i = 0; i < 4; ++i)
#pragma unroll
        for (int j = 0; j < 4; ++j) {
            int col = bn + wc + j * 16 + cl;
            float b_ = bias[col];
#pragma unroll
            for (int r = 0; r < 4; ++r) {
                int row = bm + wr + i * 16 + rb + r;
                O[(size_t)row * GN + col] = acc[i][j][r] + b_;
            }
        }
}

// ---------------- Vsum[b][e] = sum_s V[b,s,e] ----------------
__global__ __launch_bounds__(256) void vsum_kernel(const float* __restrict__ Vf, float* __restrict__ Vsum)
{
    const int b = blockIdx.y;
    const int l = threadIdx.x & 63, sg = threadIdx.x >> 6;
    const int e = blockIdx.x * 64 + l;
    float s = 0.f;
    const float* p = Vf + ((size_t)b * SEQ + sg * 256) * EMB + e;
    for (int r = 0; r < 256; ++r) s += p[(size_t)r * EMB];
    __shared__ float red[4][64];
    red[sg][l] = s;
    __syncthreads();
    if (sg == 0) Vsum[b * EMB + e] = red[0][l] + red[1][l] + red[2][l] + red[3][l];
}

// ---------------- fused local attention + residual + layernorm ----------------
__global__ __launch_bounds__(256) void attn_ln(
    const float* __restrict__ Qf, const float* __restrict__ Kf, const float* __restrict__ Vf,
    const float* __restrict__ Vsum, const float* __restrict__ am, const float* __restrict__ ww,
    const float* __restrict__ gamma, const float* __restrict__ beta, float* __restrict__ out)
{
    const int bs = blockIdx.x;              // b*SEQ + q
    const int b = bs >> 10, qq = bs & 1023;
    const int tid = threadIdx.x;
    const int lo = (qq - WIN > 0) ? qq - WIN : 0;
    const int hi = (qq + WIN < SEQ - 1) ? qq + WIN : SEQ - 1;
    const int n = hi - lo + 1;

    __shared__ float qs[EMB];
    __shared__ float sc[NHEAD][MAXW + 3];
    __shared__ float comb[NHEAD][MAXW + 3];
    __shared__ float unif[NHEAD];
    __shared__ float amw[MAXW + 3];
    __shared__ float wwl[3];
    __shared__ float r1[4], r2[4];

    // load q row + mask window + weights
    for (int e = tid; e < EMB; e += 256) qs[e] = Qf[(size_t)bs * EMB + e];
    if (tid < n) amw[tid] = am[b * SEQ + lo + tid];
    if (tid < 3) wwl[tid] = ww[tid];
    __syncthreads();

    // phase 1: in-band scores (scaled by 1/8)
    for (int idx = tid; idx < NHEAD * n; idx += 256) {
        int h = idx / n, j = idx - h * n;
        const float* kr = Kf + ((size_t)(b * SEQ + lo + j)) * EMB + h * HD;
        const float* qh = qs + h * HD;
        float d = 0.f;
#pragma unroll
        for (int t = 0; t < 16; ++t) {
            float4 kv = *(const float4*)(kr + t * 4);
            d += qh[t * 4 + 0] * kv.x + qh[t * 4 + 1] * kv.y + qh[t * 4 + 2] * kv.z + qh[t * 4 + 3] * kv.w;
        }
        sc[h][j] = d * 0.125f;
    }
    __syncthreads();

    // phase 2: 3-window softmax (bands nested -> effective mask is band16, am^iter powers)
    // 16 lanes per head; out-of-band entries are exactly 0 -> contribute exp(-max), max >= 0.
    {
        const int g = tid >> 4, sub = tid & 15;
        if (g < NHEAD) {
            float raw[3], aj[3];
            int nj = 0;
            for (int j = sub; j < n; j += 16) { raw[nj] = sc[g][j]; aj[nj] = amw[j]; ++nj; }
            float t[3], cj[3] = {0.f, 0.f, 0.f};
            for (int c = 0; c < nj; ++c) t[c] = raw[c] * aj[c];
            float myunif = 0.f;
#pragma unroll
            for (int it = 0; it < 3; ++it) {
                float m = 0.f;                       // out-of-band zeros always present (S>n)
                for (int c = 0; c < nj; ++c) m = fmaxf(m, t[c]);
                for (int o = 1; o < 16; o <<= 1) m = fmaxf(m, __shfl_xor(m, o, 64));
                float e[3], s = 0.f;
                for (int c = 0; c < nj; ++c) { e[c] = __expf(t[c] - m); s += e[c]; }
                for (int o = 1; o < 16; o <<= 1) s += __shfl_xor(s, o, 64);
                float un = __expf(-m);
                s += (float)(SEQ - n) * un;          // uniform out-of-band mass
                float inv = wwl[it] / s;
                for (int c = 0; c < nj; ++c) cj[c] += e[c] * inv;
                myunif += un * inv;
                for (int c = 0; c < nj; ++c) t[c] *= aj[c];   // next am power
            }
            for (int c = 0, j = sub; j < n; j += 16, ++c) comb[g][j] = cj[c];
            if (sub == 0) unif[g] = myunif;
        }
    }
    __syncthreads();

    // phase 3: context + residual; keep x in registers
    float xv[3];
#pragma unroll
    for (int c = 0; c < 3; ++c) {
        int e = tid + 256 * c;
        int h = e >> 6;
        float u = unif[h];
        float ctx = u * Vsum[b * EMB + e];
        const float* vp = Vf + ((size_t)(b * SEQ + lo)) * EMB + e;
        for (int j = 0; j < n; ++j)
            ctx += (comb[h][j] - u) * vp[(size_t)j * EMB];
        xv[c] = qs[e] + ctx;
    }

    // layernorm over 768
    float s1 = xv[0] + xv[1] + xv[2];
    float s2 = xv[0] * xv[0] + xv[1] * xv[1] + xv[2] * xv[2];
    for (int o = 32; o; o >>= 1) { s1 += __shfl_xor(s1, o, 64); s2 += __shfl_xor(s2, o, 64); }
    const int wave = tid >> 6, lane = tid & 63;
    if (lane == 0) { r1[wave] = s1; r2[wave] = s2; }
    __syncthreads();
    float st = r1[0] + r1[1] + r1[2] + r1[3];
    float qt = r2[0] + r2[1] + r2[2] + r2[3];
    float mean = st * (1.f / EMB);
    float var = qt * (1.f / EMB) - mean * mean;
    float rstd = rsqrtf(var + LN_EPS);
    float* orow = out + (size_t)bs * EMB;
#pragma unroll
    for (int c = 0; c < 3; ++c) {
        int e = tid + 256 * c;
        orow[e] = gamma[e] * (xv[c] - mean) * rstd + beta[e];
    }
}

// ---------------- launch ----------------
extern "C" void kernel_launch(void* const* d_in, const int* in_sizes, int n_in,
                              void* d_out, int out_size, void* d_ws, size_t ws_size,
                              hipStream_t stream)
{
    const float* q     = (const float*)d_in[0];
    const float* k     = (const float*)d_in[1];
    const float* v     = (const float*)d_in[2];
    const float* amask = (const float*)d_in[3];
    const float* Wq    = (const float*)d_in[4];
    const float* bq    = (const float*)d_in[5];
    const float* Wk    = (const float*)d_in[6];
    const float* bk    = (const float*)d_in[7];
    const float* Wv    = (const float*)d_in[8];
    const float* bv    = (const float*)d_in[9];
    const float* ww    = (const float*)d_in[10];
    const float* gamma = (const float*)d_in[11];
    const float* beta  = (const float*)d_in[12];
    float* out = (float*)d_out;

    char* ws = (char*)d_ws;
    u16*   Abf  = (u16*)ws;                              // 3 * 4096*768 bf16 = 18,874,368 B
    u16*   Wbf  = (u16*)(ws + 18874368);                 // 3 * 768*768 bf16  =  3,538,944 B
    float* QKV  = (float*)(ws + 22413312);               // 3 * 4096*768 f32  = 37,748,736 B
    float* Vsum = (float*)(ws + 60162048);               // 4*768 f32
    float* Qf = QKV, *Kf = QKV + 3145728, *Vf = QKV + 2 * 3145728;

    hipLaunchKernelGGL(cast_all, dim3(10944), dim3(256), 0, stream,
                       q, k, v, Wq, Wk, Wv, Abf, Wbf);
    hipLaunchKernelGGL(gemm_qkv, dim3(GN / 128, MROWS / 128, 3), dim3(256), 0, stream,
                       Abf, Wbf, bq, bk, bv, QKV);
    hipLaunchKernelGGL(vsum_kernel, dim3(EMB / 64, NBAT), dim3(256), 0, stream,
                       Vf, Vsum);
    hipLaunchKernelGGL(attn_ln, dim3(MROWS), dim3(256), 0, stream,
                       Qf, Kf, Vf, Vsum, amask, ww, gamma, beta, out);
}

// Round 2
// 92.007 us; speedup vs baseline: 1.8304x; 1.8304x over previous
//
#include <hip/hip_runtime.h>

#define EMB   768
#define SEQ   1024
#define NBAT  4
#define MROWS 4096      // NBAT*SEQ
#define NHEAD 12
#define HD    64
#define WIN   16
#define QB    32
#define KB    64
#define LN_EPS 1e-5f

typedef __attribute__((ext_vector_type(8))) short bf16x8;
typedef __attribute__((ext_vector_type(4))) float f32x4;
typedef unsigned short u16;
typedef unsigned int   u32;

// ---------------- cast f32 -> bf16 (RNE) ----------------
static __device__ inline u16 f2bf(float f) {
    union { float f; u32 u; } a; a.f = f;
    u32 u = a.u;
    u32 r = (u + 0x7fffu + ((u >> 16) & 1u)) >> 16;
    return (u16)r;
}

// activations: 3 arrays of 4096*768 f32; weights: 3 arrays of 768*768 f32
#define ACT4 786432u    // 4096*768/4
#define WT4  147456u    // 768*768/4
__global__ __launch_bounds__(256) void cast_all(
    const float* __restrict__ q, const float* __restrict__ k, const float* __restrict__ v,
    const float* __restrict__ wq, const float* __restrict__ wk, const float* __restrict__ wv,
    u16* __restrict__ Abf, u16* __restrict__ Wbf)
{
    u32 u = blockIdx.x * 256u + threadIdx.x;
    const float* src; u16* dst; u32 off;
    if (u < 3u * ACT4) {
        u32 which = u / ACT4;
        off = (u - which * ACT4) * 4u;
        src = which == 0 ? q : (which == 1 ? k : v);
        dst = Abf + (size_t)which * 3145728u + off;
    } else {
        u32 w2 = u - 3u * ACT4;
        u32 which = w2 / WT4;
        off = (w2 - which * WT4) * 4u;
        src = which == 0 ? wq : (which == 1 ? wk : wv);
        dst = Wbf + (size_t)which * 589824u + off;
    }
    float4 val = *(const float4*)(src + off);
    ushort4 o;
    o.x = f2bf(val.x); o.y = f2bf(val.y); o.z = f2bf(val.z); o.w = f2bf(val.w);
    *(ushort4*)dst = o;
}

// ---------------- bf16 MFMA GEMM: C[m][n] = sum_k A[m][k]*W[n][k] + bias[n] ----------------
#define GK 768
#define GN 768

static __device__ inline void gload_lds16(const void* g, void* l) {
    __builtin_amdgcn_global_load_lds((const __attribute__((address_space(1))) void*)g,
                                     (__attribute__((address_space(3))) void*)l, 16, 0, 0);
}

__global__ __launch_bounds__(256) void gemm_qkv(
    const u16* __restrict__ Abase, const u16* __restrict__ Wbase,
    const float* __restrict__ bq, const float* __restrict__ bk, const float* __restrict__ bv,
    float* __restrict__ Obase)
{
    const int z = blockIdx.z;
    const u16* A = Abase + (size_t)z * (MROWS * GK);
    const u16* W = Wbase + (size_t)z * (GN * GK);
    const float* bias = (z == 0) ? bq : ((z == 1) ? bk : bv);
    float* O = Obase + (size_t)z * (MROWS * GN);

    const int bm = blockIdx.y * 128, bn = blockIdx.x * 128;
    const int tid = threadIdx.x, wave = tid >> 6, lane = tid & 63;

    __shared__ __align__(16) u16 As[128 * 32];
    __shared__ __align__(16) u16 Bs[128 * 32];

    f32x4 acc[4][4];
#pragma unroll
    for (int i = 0; i < 4; ++i)
#pragma unroll
        for (int j = 0; j < 4; ++j) acc[i][j] = (f32x4){0.f, 0.f, 0.f, 0.f};

    const int wr = (wave >> 1) * 64, wc = (wave & 1) * 64;
    const int r0 = lane & 15, kof = (lane >> 4) * 8;

    for (int k0 = 0; k0 < GK; k0 += 32) {
#pragma unroll
        for (int j = 0; j < 2; ++j) {
            int c = (j * 4 + wave) * 64 + lane;        // 0..511
            int row = c >> 2, col = (c & 3) * 8;
            gload_lds16(A + (size_t)(bm + row) * GK + k0 + col, As + (j * 4 + wave) * 512);
            gload_lds16(W + (size_t)(bn + row) * GK + k0 + col, Bs + (j * 4 + wave) * 512);
        }
        __syncthreads();

        bf16x8 af[4], bf[4];
#pragma unroll
        for (int f = 0; f < 4; ++f) {
            af[f] = *(const bf16x8*)&As[(wr + f * 16 + r0) * 32 + kof];
            bf[f] = *(const bf16x8*)&Bs[(wc + f * 16 + r0) * 32 + kof];
        }
#pragma unroll
        for (int i = 0; i < 4; ++i)
#pragma unroll
            for (int j = 0; j < 4; ++j)
                acc[i][j] = __builtin_amdgcn_mfma_f32_16x16x32_bf16(af[i], bf[j], acc[i][j], 0, 0, 0);
        __syncthreads();
    }

    const int cl = lane & 15, rb = (lane >> 4) * 4;
#pragma unroll
    for (int i = 0; i < 4; ++i)
#pragma unroll
        for (int j = 0; j < 4; ++j) {
            int col = bn + wc + j * 16 + cl;
            float b_ = bias[col];
#pragma unroll
            for (int r = 0; r < 4; ++r) {
                int row = bm + wr + i * 16 + rb + r;
                O[(size_t)row * GN + col] = acc[i][j][r] + b_;
            }
        }
}

// ---------------- Vsum[b][e] = sum_s V[b,s,e] ----------------
__global__ __launch_bounds__(256) void vsum_kernel(const float* __restrict__ Vf, float* __restrict__ Vsum)
{
    const int b = blockIdx.y;
    const int l = threadIdx.x & 63, sg = threadIdx.x >> 6;
    const int e = blockIdx.x * 64 + l;
    float s = 0.f;
    const float* p = Vf + ((size_t)b * SEQ + sg * 256) * EMB + e;
    for (int r = 0; r < 256; ++r) s += p[(size_t)r * EMB];
    __shared__ float red[4][64];
    red[sg][l] = s;
    __syncthreads();
    if (sg == 0) Vsum[b * EMB + e] = red[0][l] + red[1][l] + red[2][l] + red[3][l];
}

// ---------------- MFMA local attention: per (b, qtile32, head) -> context ----------------
// Effective mask is band16 (nested bands); out-of-band keys get uniform weight exp(-m)/Z.
// ctx[q][:] = sum_tile (p_k - u) v_k + u * Vsum.
__global__ __launch_bounds__(64) void attn_mfma(
    const float* __restrict__ Qf, const float* __restrict__ Kf, const float* __restrict__ Vf,
    const float* __restrict__ Vsum, const float* __restrict__ am, const float* __restrict__ ww,
    float* __restrict__ ctx)
{
    const int qt = blockIdx.x, h = blockIdx.y, b = blockIdx.z;
    const int q0 = qt * QB;
    int kstart = q0 - WIN;
    if (kstart < 0) kstart = 0;
    if (kstart > SEQ - KB) kstart = SEQ - KB;
    const int lane = threadIdx.x;

    __shared__ __align__(16) u16 Qs[QB][72];
    __shared__ __align__(16) u16 Ks[KB][72];
    __shared__ __align__(16) u16 Vt[KB][72];   // Vt[d][k]
    __shared__ __align__(16) u16 Ps[QB][72];

    const float w0 = ww[0], w1 = ww[1], w2 = ww[2];

    // ---- stage Q (32x64), K (64x64), V^T (64x64) as bf16 ----
    {
        const float* qbase = Qf + ((size_t)(b * SEQ + q0)) * EMB + h * HD;
#pragma unroll
        for (int it = 0; it < 8; ++it) {
            int idx = it * 64 + lane;
            int row = idx >> 4, c4 = (idx & 15) * 4;
            float4 vv = *(const float4*)(qbase + (size_t)row * EMB + c4);
            ushort4 o; o.x = f2bf(vv.x); o.y = f2bf(vv.y); o.z = f2bf(vv.z); o.w = f2bf(vv.w);
            *(ushort4*)&Qs[row][c4] = o;
        }
        const float* kbase = Kf + ((size_t)(b * SEQ + kstart)) * EMB + h * HD;
        const float* vbase = Vf + ((size_t)(b * SEQ + kstart)) * EMB + h * HD;
#pragma unroll
        for (int it = 0; it < 16; ++it) {
            int idx = it * 64 + lane;
            int row = idx >> 4, c4 = (idx & 15) * 4;
            float4 kv = *(const float4*)(kbase + (size_t)row * EMB + c4);
            ushort4 o; o.x = f2bf(kv.x); o.y = f2bf(kv.y); o.z = f2bf(kv.z); o.w = f2bf(kv.w);
            *(ushort4*)&Ks[row][c4] = o;
            float4 vv = *(const float4*)(vbase + (size_t)row * EMB + c4);
            Vt[c4 + 0][row] = f2bf(vv.x); Vt[c4 + 1][row] = f2bf(vv.y);
            Vt[c4 + 2][row] = f2bf(vv.z); Vt[c4 + 3][row] = f2bf(vv.w);
        }
    }
    __syncthreads();

    const int fr = lane & 15, kof = (lane >> 4) * 8;
    const int rowg = (lane >> 4) * 4;

    // ---- QK^T: 32x64 over K=64 ----
    f32x4 sc[2][4];
#pragma unroll
    for (int i = 0; i < 2; ++i)
#pragma unroll
        for (int j = 0; j < 4; ++j) sc[i][j] = (f32x4){0.f, 0.f, 0.f, 0.f};
#pragma unroll
    for (int kk = 0; kk < 2; ++kk) {
        bf16x8 aq[2], bk4[4];
#pragma unroll
        for (int mi = 0; mi < 2; ++mi) aq[mi] = *(const bf16x8*)&Qs[mi * 16 + fr][kk * 32 + kof];
#pragma unroll
        for (int nj = 0; nj < 4; ++nj) bk4[nj] = *(const bf16x8*)&Ks[nj * 16 + fr][kk * 32 + kof];
#pragma unroll
        for (int mi = 0; mi < 2; ++mi)
#pragma unroll
            for (int nj = 0; nj < 4; ++nj)
                sc[mi][nj] = __builtin_amdgcn_mfma_f32_16x16x32_bf16(aq[mi], bk4[nj], sc[mi][nj], 0, 0, 0);
    }

    // ---- per-row softmax over the band + analytic uniform tail ----
    float amv[4];
#pragma unroll
    for (int nj = 0; nj < 4; ++nj) amv[nj] = am[b * SEQ + kstart + nj * 16 + fr];

    float t[2][4][4], cj[2][4][4], ua[2][4];
#pragma unroll
    for (int mi = 0; mi < 2; ++mi)
#pragma unroll
        for (int nj = 0; nj < 4; ++nj)
#pragma unroll
            for (int r = 0; r < 4; ++r) {
                int qrow = q0 + mi * 16 + rowg + r;
                int kcol = kstart + nj * 16 + fr;
                int d = qrow - kcol; if (d < 0) d = -d;
                t[mi][nj][r] = (d <= WIN) ? sc[mi][nj][r] * 0.125f * amv[nj] : 0.f;
                cj[mi][nj][r] = 0.f;
            }
#pragma unroll
    for (int mi = 0; mi < 2; ++mi)
#pragma unroll
        for (int r = 0; r < 4; ++r) ua[mi][r] = 0.f;

    float e[2][4][4];
#pragma unroll
    for (int it = 0; it < 3; ++it) {
        float wwi = it == 0 ? w0 : (it == 1 ? w1 : w2);
#pragma unroll
        for (int mi = 0; mi < 2; ++mi)
#pragma unroll
            for (int r = 0; r < 4; ++r) {
                float m = 0.f;   // out-of-tile zeros always present
#pragma unroll
                for (int nj = 0; nj < 4; ++nj) m = fmaxf(m, t[mi][nj][r]);
#pragma unroll
                for (int o = 1; o < 16; o <<= 1) m = fmaxf(m, __shfl_xor(m, o, 64));
                float s = 0.f;
#pragma unroll
                for (int nj = 0; nj < 4; ++nj) { e[mi][nj][r] = __expf(t[mi][nj][r] - m); s += e[mi][nj][r]; }
#pragma unroll
                for (int o = 1; o < 16; o <<= 1) s += __shfl_xor(s, o, 64);
                float un = __expf(-m);
                s += (float)(SEQ - KB) * un;
                float inv = wwi / s;
#pragma unroll
                for (int nj = 0; nj < 4; ++nj) cj[mi][nj][r] += e[mi][nj][r] * inv;
                ua[mi][r] += un * inv;
            }
        if (it < 2) {
#pragma unroll
            for (int mi = 0; mi < 2; ++mi)
#pragma unroll
                for (int nj = 0; nj < 4; ++nj)
#pragma unroll
                    for (int r = 0; r < 4; ++r) t[mi][nj][r] *= amv[nj];
        }
    }

    // ---- P' = cj - u  -> LDS (relayout to A-fragment) ----
#pragma unroll
    for (int mi = 0; mi < 2; ++mi)
#pragma unroll
        for (int nj = 0; nj < 4; ++nj)
#pragma unroll
            for (int r = 0; r < 4; ++r)
                Ps[mi * 16 + rowg + r][nj * 16 + fr] = f2bf(cj[mi][nj][r] - ua[mi][r]);
    __syncthreads();

    // ---- PV: context = P' @ V  (+ u * Vsum) ----
    f32x4 pv[2][4];
#pragma unroll
    for (int i = 0; i < 2; ++i)
#pragma unroll
        for (int j = 0; j < 4; ++j) pv[i][j] = (f32x4){0.f, 0.f, 0.f, 0.f};
#pragma unroll
    for (int kk = 0; kk < 2; ++kk) {
        bf16x8 ap[2], bv4[4];
#pragma unroll
        for (int mi = 0; mi < 2; ++mi) ap[mi] = *(const bf16x8*)&Ps[mi * 16 + fr][kk * 32 + kof];
#pragma unroll
        for (int nj = 0; nj < 4; ++nj) bv4[nj] = *(const bf16x8*)&Vt[nj * 16 + fr][kk * 32 + kof];
#pragma unroll
        for (int mi = 0; mi < 2; ++mi)
#pragma unroll
            for (int nj = 0; nj < 4; ++nj)
                pv[mi][nj] = __builtin_amdgcn_mfma_f32_16x16x32_bf16(ap[mi], bv4[nj], pv[mi][nj], 0, 0, 0);
    }

    float vs[4];
#pragma unroll
    for (int nj = 0; nj < 4; ++nj) vs[nj] = Vsum[b * EMB + h * HD + nj * 16 + fr];
#pragma unroll
    for (int mi = 0; mi < 2; ++mi)
#pragma unroll
        for (int nj = 0; nj < 4; ++nj)
#pragma unroll
            for (int r = 0; r < 4; ++r) {
                int row = q0 + mi * 16 + rowg + r;
                ctx[((size_t)(b * SEQ + row)) * EMB + h * HD + nj * 16 + fr] =
                    pv[mi][nj][r] + ua[mi][r] * vs[nj];
            }
}

// ---------------- residual + layernorm ----------------
__global__ __launch_bounds__(256) void ln_kernel(
    const float* __restrict__ Qf, const float* __restrict__ ctxb,
    const float* __restrict__ gamma, const float* __restrict__ beta, float* __restrict__ out)
{
    const int row = blockIdx.x * 4 + (threadIdx.x >> 6);
    const int lane = threadIdx.x & 63;
    const float* qr = Qf + (size_t)row * EMB;
    const float* cr = ctxb + (size_t)row * EMB;
    float x[12];
    float s1 = 0.f, s2 = 0.f;
#pragma unroll
    for (int j = 0; j < 3; ++j) {
        int e0 = j * 256 + lane * 4;
        float4 a = *(const float4*)(qr + e0);
        float4 c = *(const float4*)(cr + e0);
        float4 xx = {a.x + c.x, a.y + c.y, a.z + c.z, a.w + c.w};
        x[j * 4 + 0] = xx.x; x[j * 4 + 1] = xx.y; x[j * 4 + 2] = xx.z; x[j * 4 + 3] = xx.w;
        s1 += xx.x + xx.y + xx.z + xx.w;
        s2 += xx.x * xx.x + xx.y * xx.y + xx.z * xx.z + xx.w * xx.w;
    }
#pragma unroll
    for (int o = 32; o; o >>= 1) { s1 += __shfl_xor(s1, o, 64); s2 += __shfl_xor(s2, o, 64); }
    float mean = s1 * (1.f / EMB);
    float var = s2 * (1.f / EMB) - mean * mean;
    float rstd = rsqrtf(var + LN_EPS);
    float* orow = out + (size_t)row * EMB;
#pragma unroll
    for (int j = 0; j < 3; ++j) {
        int e0 = j * 256 + lane * 4;
        float4 g = *(const float4*)(gamma + e0);
        float4 be = *(const float4*)(beta + e0);
        float4 o;
        o.x = g.x * (x[j * 4 + 0] - mean) * rstd + be.x;
        o.y = g.y * (x[j * 4 + 1] - mean) * rstd + be.y;
        o.z = g.z * (x[j * 4 + 2] - mean) * rstd + be.z;
        o.w = g.w * (x[j * 4 + 3] - mean) * rstd + be.w;
        *(float4*)(orow + e0) = o;
    }
}

// ---------------- launch ----------------
extern "C" void kernel_launch(void* const* d_in, const int* in_sizes, int n_in,
                              void* d_out, int out_size, void* d_ws, size_t ws_size,
                              hipStream_t stream)
{
    const float* q     = (const float*)d_in[0];
    const float* k     = (const float*)d_in[1];
    const float* v     = (const float*)d_in[2];
    const float* amask = (const float*)d_in[3];
    const float* Wq    = (const float*)d_in[4];
    const float* bq    = (const float*)d_in[5];
    const float* Wk    = (const float*)d_in[6];
    const float* bk    = (const float*)d_in[7];
    const float* Wv    = (const float*)d_in[8];
    const float* bv    = (const float*)d_in[9];
    const float* ww    = (const float*)d_in[10];
    const float* gamma = (const float*)d_in[11];
    const float* beta  = (const float*)d_in[12];
    float* out = (float*)d_out;

    char* ws = (char*)d_ws;
    u16*   Abf  = (u16*)ws;                    // 3 * 4096*768 bf16 = 18,874,368 B (dead after GEMM)
    u16*   Wbf  = (u16*)(ws + 18874368);       // 3 * 768*768 bf16
    float* QKV  = (float*)(ws + 22413312);     // 3 * 4096*768 f32
    float* Vsum = (float*)(ws + 60162048);     // 4*768 f32
    float* ctx  = (float*)ws;                  // 12.58 MB, aliases Abf (safe: stream-ordered)
    float* Qf = QKV, *Kf = QKV + 3145728, *Vf = QKV + 2 * 3145728;

    hipLaunchKernelGGL(cast_all, dim3(10944), dim3(256), 0, stream,
                       q, k, v, Wq, Wk, Wv, Abf, Wbf);
    hipLaunchKernelGGL(gemm_qkv, dim3(GN / 128, MROWS / 128, 3), dim3(256), 0, stream,
                       Abf, Wbf, bq, bk, bv, QKV);
    hipLaunchKernelGGL(vsum_kernel, dim3(EMB / 64, NBAT), dim3(256), 0, stream,
                       Vf, Vsum);
    hipLaunchKernelGGL(attn_mfma, dim3(SEQ / QB, NHEAD, NBAT), dim3(64), 0, stream,
                       Qf, Kf, Vf, Vsum, amask, ww, ctx);
    hipLaunchKernelGGL(ln_kernel, dim3(MROWS / 4), dim3(256), 0, stream,
                       Qf, ctx, gamma, beta, out);
}

// Round 3
// 87.841 us; speedup vs baseline: 1.9173x; 1.0474x over previous
//
#include <hip/hip_runtime.h>
#include <hip/hip_bf16.h>

#define EMB   768
#define SEQ   1024
#define NBAT  4
#define MROWS 4096      // NBAT*SEQ
#define NHEAD 12
#define HD    64
#define WIN   16
#define QB    32
#define KB    64
#define LN_EPS 1e-5f

typedef __attribute__((ext_vector_type(8))) short bf16x8;
typedef __attribute__((ext_vector_type(4))) float f32x4;
typedef unsigned short u16;
typedef unsigned int   u32;

// ---------------- f32 -> bf16 conversions (RNE) ----------------
static __device__ inline u16 f2bf(float f) {
    union { float f; u32 u; } a; a.f = f;
    u32 u = a.u;
    u32 r = (u + 0x7fffu + ((u >> 16) & 1u)) >> 16;
    return (u16)r;
}
static __device__ inline u32 cvt2(float lo, float hi) {
    __hip_bfloat162 t = __float22bfloat162_rn(float2{lo, hi});
    union { __hip_bfloat162 h; u32 u; } c; c.h = t; return c.u;
}
static __device__ inline bf16x8 pack8(float4 a, float4 b) {
    union { bf16x8 v; u32 w[4]; } r;
    r.w[0] = cvt2(a.x, a.y); r.w[1] = cvt2(a.z, a.w);
    r.w[2] = cvt2(b.x, b.y); r.w[3] = cvt2(b.z, b.w);
    return r.v;
}

// ---------------- fused cast + bf16 MFMA GEMM ----------------
// C[m][n] = sum_k A[m][k]*W[n][k] + bias[n]; A,W read as f32, converted in-register.
// 128x128 tile, BK=32, 4 waves (2x2 of 64x64), double register-set staging,
// XCD-aware tile swizzle (6 same-A-row tiles land on one XCD's L2).
#define GK 768
#define GN 768

__global__ __launch_bounds__(256) void gemm_qkv(
    const float* __restrict__ qa, const float* __restrict__ ka, const float* __restrict__ va,
    const float* __restrict__ Wq, const float* __restrict__ Wk, const float* __restrict__ Wv,
    const float* __restrict__ bq, const float* __restrict__ bk, const float* __restrict__ bv,
    float* __restrict__ Obase)
{
    const int z = blockIdx.z;
    const float* A = (z == 0) ? qa : ((z == 1) ? ka : va);
    const float* W = (z == 0) ? Wq : ((z == 1) ? Wk : Wv);
    const float* bias = (z == 0) ? bq : ((z == 1) ? bk : bv);
    float* O = Obase + (size_t)z * (MROWS * GN);

    // XCD swizzle within this z-slice: 192 tiles, 24 contiguous per XCD (= 4 A-panels)
    int id = blockIdx.y * 6 + blockIdx.x;
    int swz = (id & 7) * 24 + (id >> 3);
    const int bm = (swz / 6) * 128, bn = (swz % 6) * 128;

    const int tid = threadIdx.x, wave = tid >> 6, lane = tid & 63;

    __shared__ __align__(16) u16 As[128 * 32];
    __shared__ __align__(16) u16 Bs[128 * 32];

    f32x4 acc[4][4];
#pragma unroll
    for (int i = 0; i < 4; ++i)
#pragma unroll
        for (int j = 0; j < 4; ++j) acc[i][j] = (f32x4){0.f, 0.f, 0.f, 0.f};

    const int wr = (wave >> 1) * 64, wc = (wave & 1) * 64;
    const int r0 = lane & 15, kof = (lane >> 4) * 8;

    // staging mapping: thread t covers chunks (row, c8) and (row+64, c8)
    const int srow = tid >> 2, sc8 = (tid & 3) * 8;
    const float* arow0 = A + (size_t)(bm + srow) * GK + sc8;
    const float* wrow0 = W + (size_t)(bn + srow) * GK + sc8;

    float4 a0, a1, a2, a3, w0, w1, w2, w3;     // set 0
    float4 b0, b1, b2, b3, x0, x1, x2, x3;     // set 1

#define LOADS0(K0) { const float* p = arow0 + (K0); \
    a0 = *(const float4*)p; a1 = *(const float4*)(p + 4); \
    a2 = *(const float4*)(p + 64 * GK); a3 = *(const float4*)(p + 64 * GK + 4); \
    const float* pw = wrow0 + (K0); \
    w0 = *(const float4*)pw; w1 = *(const float4*)(pw + 4); \
    w2 = *(const float4*)(pw + 64 * GK); w3 = *(const float4*)(pw + 64 * GK + 4); }
#define LOADS1(K0) { const float* p = arow0 + (K0); \
    b0 = *(const float4*)p; b1 = *(const float4*)(p + 4); \
    b2 = *(const float4*)(p + 64 * GK); b3 = *(const float4*)(p + 64 * GK + 4); \
    const float* pw = wrow0 + (K0); \
    x0 = *(const float4*)pw; x1 = *(const float4*)(pw + 4); \
    x2 = *(const float4*)(pw + 64 * GK); x3 = *(const float4*)(pw + 64 * GK + 4); }
#define WRITES0() { \
    *(bf16x8*)&As[srow * 32 + sc8] = pack8(a0, a1); \
    *(bf16x8*)&As[(srow + 64) * 32 + sc8] = pack8(a2, a3); \
    *(bf16x8*)&Bs[srow * 32 + sc8] = pack8(w0, w1); \
    *(bf16x8*)&Bs[(srow + 64) * 32 + sc8] = pack8(w2, w3); }
#define WRITES1() { \
    *(bf16x8*)&As[srow * 32 + sc8] = pack8(b0, b1); \
    *(bf16x8*)&As[(srow + 64) * 32 + sc8] = pack8(b2, b3); \
    *(bf16x8*)&Bs[srow * 32 + sc8] = pack8(x0, x1); \
    *(bf16x8*)&Bs[(srow + 64) * 32 + sc8] = pack8(x2, x3); }
#define COMPUTE() { bf16x8 af[4], bf[4]; \
    _Pragma("unroll") for (int f = 0; f < 4; ++f) { \
        af[f] = *(const bf16x8*)&As[(wr + f * 16 + r0) * 32 + kof]; \
        bf[f] = *(const bf16x8*)&Bs[(wc + f * 16 + r0) * 32 + kof]; } \
    _Pragma("unroll") for (int i = 0; i < 4; ++i) \
    _Pragma("unroll") for (int j = 0; j < 4; ++j) \
        acc[i][j] = __builtin_amdgcn_mfma_f32_16x16x32_bf16(af[i], bf[j], acc[i][j], 0, 0, 0); }

    LOADS0(0);
    for (int k0 = 0; k0 < GK; k0 += 64) {
        __syncthreads();
        if (k0 + 32 < GK) LOADS1(k0 + 32);
        WRITES0();
        __syncthreads();
        COMPUTE();
        __syncthreads();
        if (k0 + 64 < GK) LOADS0(k0 + 64);
        WRITES1();
        __syncthreads();
        COMPUTE();
    }

    const int cl = lane & 15, rb = (lane >> 4) * 4;
#pragma unroll
    for (int i = 0; i < 4; ++i)
#pragma unroll
        for (int j = 0; j < 4; ++j) {
            int col = bn + wc + j * 16 + cl;
            float b_ = bias[col];
#pragma unroll
            for (int r = 0; r < 4; ++r) {
                int row = bm + wr + i * 16 + rb + r;
                O[(size_t)row * GN + col] = acc[i][j][r] + b_;
            }
        }
#undef LOADS0
#undef LOADS1
#undef WRITES0
#undef WRITES1
#undef COMPUTE
}

// ---------------- Vsum[b][e] = sum_s V[b,s,e] ----------------
__global__ __launch_bounds__(256) void vsum_kernel(const float* __restrict__ Vf, float* __restrict__ Vsum)
{
    const int b = blockIdx.y;
    const int l = threadIdx.x & 63, sg = threadIdx.x >> 6;
    const int e = blockIdx.x * 64 + l;
    float s = 0.f;
    const float* p = Vf + ((size_t)b * SEQ + sg * 256) * EMB + e;
    for (int r = 0; r < 256; ++r) s += p[(size_t)r * EMB];
    __shared__ float red[4][64];
    red[sg][l] = s;
    __syncthreads();
    if (sg == 0) Vsum[b * EMB + e] = red[0][l] + red[1][l] + red[2][l] + red[3][l];
}

// ---------------- MFMA local attention ----------------
// Q,K fragments loaded per-lane directly from global (f32->bf16 in-register);
// LDS only for V^T and the P relayout. One barrier per block.
__global__ __launch_bounds__(64) void attn_mfma(
    const float* __restrict__ Qf, const float* __restrict__ Kf, const float* __restrict__ Vf,
    const float* __restrict__ Vsum, const float* __restrict__ am, const float* __restrict__ ww,
    float* __restrict__ ctx)
{
    // XCD swizzle: 1536 blocks, 192 contiguous per XCD (= 6 full (b,h) K/V slices)
    int id = blockIdx.x + 32 * (blockIdx.y + 12 * blockIdx.z);
    int swz = (id & 7) * 192 + (id >> 3);
    const int qt = swz & 31, h = (swz >> 5) % 12, b = swz / 384;

    const int q0 = qt * QB;
    int kstart = q0 - WIN;
    if (kstart < 0) kstart = 0;
    if (kstart > SEQ - KB) kstart = SEQ - KB;
    const int lane = threadIdx.x;
    const int fr = lane & 15, kof = (lane >> 4) * 8;
    const int rowg = (lane >> 4) * 4;

    __shared__ __align__(16) u16 Vt[KB][72];   // Vt[d][k]
    __shared__ __align__(16) u16 Ps[QB][72];

    const float w0 = ww[0], w1 = ww[1], w2 = ww[2];

    // ---- Q,K fragments direct from global ----
    bf16x8 aq[2][2], bk4[4][2];
    {
        const float* qb = Qf + ((size_t)(b * SEQ + q0)) * EMB + h * HD;
#pragma unroll
        for (int mi = 0; mi < 2; ++mi)
#pragma unroll
            for (int kk = 0; kk < 2; ++kk) {
                const float* p = qb + (size_t)(mi * 16 + fr) * EMB + kk * 32 + kof;
                aq[mi][kk] = pack8(*(const float4*)p, *(const float4*)(p + 4));
            }
        const float* kb = Kf + ((size_t)(b * SEQ + kstart)) * EMB + h * HD;
#pragma unroll
        for (int nj = 0; nj < 4; ++nj)
#pragma unroll
            for (int kk = 0; kk < 2; ++kk) {
                const float* p = kb + (size_t)(nj * 16 + fr) * EMB + kk * 32 + kof;
                bk4[nj][kk] = pack8(*(const float4*)p, *(const float4*)(p + 4));
            }
    }

    // ---- stage V^T (only LDS-staged operand) ----
    {
        const float* vbase = Vf + ((size_t)(b * SEQ + kstart)) * EMB + h * HD;
#pragma unroll
        for (int it = 0; it < 16; ++it) {
            int idx = it * 64 + lane;
            int row = idx >> 4, c4 = (idx & 15) * 4;
            float4 vv = *(const float4*)(vbase + (size_t)row * EMB + c4);
            Vt[c4 + 0][row] = f2bf(vv.x); Vt[c4 + 1][row] = f2bf(vv.y);
            Vt[c4 + 2][row] = f2bf(vv.z); Vt[c4 + 3][row] = f2bf(vv.w);
        }
    }

    // ---- QK^T: 32x64 over K=64 (registers only) ----
    f32x4 sc[2][4];
#pragma unroll
    for (int i = 0; i < 2; ++i)
#pragma unroll
        for (int j = 0; j < 4; ++j) sc[i][j] = (f32x4){0.f, 0.f, 0.f, 0.f};
#pragma unroll
    for (int kk = 0; kk < 2; ++kk)
#pragma unroll
        for (int mi = 0; mi < 2; ++mi)
#pragma unroll
            for (int nj = 0; nj < 4; ++nj)
                sc[mi][nj] = __builtin_amdgcn_mfma_f32_16x16x32_bf16(aq[mi][kk], bk4[nj][kk], sc[mi][nj], 0, 0, 0);

    // ---- per-row softmax over band + analytic uniform tail ----
    float amv[4];
#pragma unroll
    for (int nj = 0; nj < 4; ++nj) amv[nj] = am[b * SEQ + kstart + nj * 16 + fr];

    float t[2][4][4], cj[2][4][4], ua[2][4];
#pragma unroll
    for (int mi = 0; mi < 2; ++mi)
#pragma unroll
        for (int nj = 0; nj < 4; ++nj)
#pragma unroll
            for (int r = 0; r < 4; ++r) {
                int qrow = q0 + mi * 16 + rowg + r;
                int kcol = kstart + nj * 16 + fr;
                int d = qrow - kcol; if (d < 0) d = -d;
                t[mi][nj][r] = (d <= WIN) ? sc[mi][nj][r] * 0.125f * amv[nj] : 0.f;
                cj[mi][nj][r] = 0.f;
            }
#pragma unroll
    for (int mi = 0; mi < 2; ++mi)
#pragma unroll
        for (int r = 0; r < 4; ++r) ua[mi][r] = 0.f;

#pragma unroll
    for (int it = 0; it < 3; ++it) {
        float wwi = it == 0 ? w0 : (it == 1 ? w1 : w2);
#pragma unroll
        for (int mi = 0; mi < 2; ++mi)
#pragma unroll
            for (int r = 0; r < 4; ++r) {
                float m = 0.f;   // out-of-tile zeros always present
#pragma unroll
                for (int nj = 0; nj < 4; ++nj) m = fmaxf(m, t[mi][nj][r]);
#pragma unroll
                for (int o = 1; o < 16; o <<= 1) m = fmaxf(m, __shfl_xor(m, o, 64));
                float e4[4], s = 0.f;
#pragma unroll
                for (int nj = 0; nj < 4; ++nj) { e4[nj] = __expf(t[mi][nj][r] - m); s += e4[nj]; }
#pragma unroll
                for (int o = 1; o < 16; o <<= 1) s += __shfl_xor(s, o, 64);
                float un = __expf(-m);
                s += (float)(SEQ - KB) * un;
                float inv = wwi / s;
#pragma unroll
                for (int nj = 0; nj < 4; ++nj) cj[mi][nj][r] += e4[nj] * inv;
                ua[mi][r] += un * inv;
            }
        if (it < 2) {
#pragma unroll
            for (int mi = 0; mi < 2; ++mi)
#pragma unroll
                for (int nj = 0; nj < 4; ++nj)
#pragma unroll
                    for (int r = 0; r < 4; ++r) t[mi][nj][r] *= amv[nj];
        }
    }

    // ---- P' = cj - u -> LDS (relayout to A-fragment) ----
#pragma unroll
    for (int mi = 0; mi < 2; ++mi)
#pragma unroll
        for (int nj = 0; nj < 4; ++nj)
#pragma unroll
            for (int r = 0; r < 4; ++r)
                Ps[mi * 16 + rowg + r][nj * 16 + fr] = f2bf(cj[mi][nj][r] - ua[mi][r]);
    __syncthreads();

    // ---- PV: context = P' @ V (+ u * Vsum) ----
    f32x4 pv[2][4];
#pragma unroll
    for (int i = 0; i < 2; ++i)
#pragma unroll
        for (int j = 0; j < 4; ++j) pv[i][j] = (f32x4){0.f, 0.f, 0.f, 0.f};
#pragma unroll
    for (int kk = 0; kk < 2; ++kk) {
        bf16x8 ap[2], bv4[4];
#pragma unroll
        for (int mi = 0; mi < 2; ++mi) ap[mi] = *(const bf16x8*)&Ps[mi * 16 + fr][kk * 32 + kof];
#pragma unroll
        for (int nj = 0; nj < 4; ++nj) bv4[nj] = *(const bf16x8*)&Vt[nj * 16 + fr][kk * 32 + kof];
#pragma unroll
        for (int mi = 0; mi < 2; ++mi)
#pragma unroll
            for (int nj = 0; nj < 4; ++nj)
                pv[mi][nj] = __builtin_amdgcn_mfma_f32_16x16x32_bf16(ap[mi], bv4[nj], pv[mi][nj], 0, 0, 0);
    }

    float vs[4];
#pragma unroll
    for (int nj = 0; nj < 4; ++nj) vs[nj] = Vsum[b * EMB + h * HD + nj * 16 + fr];
#pragma unroll
    for (int mi = 0; mi < 2; ++mi)
#pragma unroll
        for (int nj = 0; nj < 4; ++nj)
#pragma unroll
            for (int r = 0; r < 4; ++r) {
                int row = q0 + mi * 16 + rowg + r;
                ctx[((size_t)(b * SEQ + row)) * EMB + h * HD + nj * 16 + fr] =
                    pv[mi][nj][r] + ua[mi][r] * vs[nj];
            }
}

// ---------------- residual + layernorm ----------------
__global__ __launch_bounds__(256) void ln_kernel(
    const float* __restrict__ Qf, const float* __restrict__ ctxb,
    const float* __restrict__ gamma, const float* __restrict__ beta, float* __restrict__ out)
{
    const int row = blockIdx.x * 4 + (threadIdx.x >> 6);
    const int lane = threadIdx.x & 63;
    const float* qr = Qf + (size_t)row * EMB;
    const float* cr = ctxb + (size_t)row * EMB;
    float x[12];
    float s1 = 0.f, s2 = 0.f;
#pragma unroll
    for (int j = 0; j < 3; ++j) {
        int e0 = j * 256 + lane * 4;
        float4 a = *(const float4*)(qr + e0);
        float4 c = *(const float4*)(cr + e0);
        float4 xx = {a.x + c.x, a.y + c.y, a.z + c.z, a.w + c.w};
        x[j * 4 + 0] = xx.x; x[j * 4 + 1] = xx.y; x[j * 4 + 2] = xx.z; x[j * 4 + 3] = xx.w;
        s1 += xx.x + xx.y + xx.z + xx.w;
        s2 += xx.x * xx.x + xx.y * xx.y + xx.z * xx.z + xx.w * xx.w;
    }
#pragma unroll
    for (int o = 32; o; o >>= 1) { s1 += __shfl_xor(s1, o, 64); s2 += __shfl_xor(s2, o, 64); }
    float mean = s1 * (1.f / EMB);
    float var = s2 * (1.f / EMB) - mean * mean;
    float rstd = rsqrtf(var + LN_EPS);
    float* orow = out + (size_t)row * EMB;
#pragma unroll
    for (int j = 0; j < 3; ++j) {
        int e0 = j * 256 + lane * 4;
        float4 g = *(const float4*)(gamma + e0);
        float4 be = *(const float4*)(beta + e0);
        float4 o;
        o.x = g.x * (x[j * 4 + 0] - mean) * rstd + be.x;
        o.y = g.y * (x[j * 4 + 1] - mean) * rstd + be.y;
        o.z = g.z * (x[j * 4 + 2] - mean) * rstd + be.z;
        o.w = g.w * (x[j * 4 + 3] - mean) * rstd + be.w;
        *(float4*)(orow + e0) = o;
    }
}

// ---------------- launch ----------------
extern "C" void kernel_launch(void* const* d_in, const int* in_sizes, int n_in,
                              void* d_out, int out_size, void* d_ws, size_t ws_size,
                              hipStream_t stream)
{
    const float* q     = (const float*)d_in[0];
    const float* k     = (const float*)d_in[1];
    const float* v     = (const float*)d_in[2];
    const float* amask = (const float*)d_in[3];
    const float* Wq    = (const float*)d_in[4];
    const float* bq    = (const float*)d_in[5];
    const float* Wk    = (const float*)d_in[6];
    const float* bk    = (const float*)d_in[7];
    const float* Wv    = (const float*)d_in[8];
    const float* bv    = (const float*)d_in[9];
    const float* ww    = (const float*)d_in[10];
    const float* gamma = (const float*)d_in[11];
    const float* beta  = (const float*)d_in[12];
    float* out = (float*)d_out;

    char* ws = (char*)d_ws;
    float* ctx  = (float*)ws;                  // 12,582,912 B
    float* QKV  = (float*)(ws + 16777216);     // 37,748,736 B
    float* Vsum = (float*)(ws + 54525952);     // 12,288 B
    float* Qf = QKV, *Kf = QKV + 3145728, *Vf = QKV + 2 * 3145728;

    hipLaunchKernelGGL(gemm_qkv, dim3(GN / 128, MROWS / 128, 3), dim3(256), 0, stream,
                       q, k, v, Wq, Wk, Wv, bq, bk, bv, QKV);
    hipLaunchKernelGGL(vsum_kernel, dim3(EMB / 64, NBAT), dim3(256), 0, stream,
                       Vf, Vsum);
    hipLaunchKernelGGL(attn_mfma, dim3(SEQ / QB, NHEAD, NBAT), dim3(64), 0, stream,
                       Qf, Kf, Vf, Vsum, amask, ww, ctx);
    hipLaunchKernelGGL(ln_kernel, dim3(MROWS / 4), dim3(256), 0, stream,
                       Qf, ctx, gamma, beta, out);
}

// Round 4
// 83.616 us; speedup vs baseline: 2.0141x; 1.0505x over previous
//
#include <hip/hip_runtime.h>
#include <hip/hip_bf16.h>

#define EMB   768
#define SEQ   1024
#define NBAT  4
#define MROWS 4096      // NBAT*SEQ
#define NHEAD 12
#define HD    64
#define WIN   16
#define QB    32
#define KB    64
#define LN_EPS 1e-5f

typedef __attribute__((ext_vector_type(8))) short bf16x8;
typedef __attribute__((ext_vector_type(4))) float f32x4;
typedef unsigned short u16;
typedef unsigned int   u32;

// ---------------- f32 <-> bf16 helpers ----------------
static __device__ inline u16 f2bf(float f) {
    union { float f; u32 u; } a; a.f = f;
    u32 u = a.u;
    u32 r = (u + 0x7fffu + ((u >> 16) & 1u)) >> 16;
    return (u16)r;
}
static __device__ inline float bf2f(u16 x) {
    union { u32 u; float f; } c; c.u = ((u32)x) << 16; return c.f;
}

// ---------------- cast f32 -> bf16 (activations + weights) ----------------
#define ACT4 786432u    // 4096*768/4
#define WT4  147456u    // 768*768/4
__global__ __launch_bounds__(256) void cast_all(
    const float* __restrict__ q, const float* __restrict__ k, const float* __restrict__ v,
    const float* __restrict__ wq, const float* __restrict__ wk, const float* __restrict__ wv,
    u16* __restrict__ Abf, u16* __restrict__ Wbf)
{
    u32 u = blockIdx.x * 256u + threadIdx.x;
    const float* src; u16* dst; u32 off;
    if (u < 3u * ACT4) {
        u32 which = u / ACT4;
        off = (u - which * ACT4) * 4u;
        src = which == 0 ? q : (which == 1 ? k : v);
        dst = Abf + (size_t)which * 3145728u + off;
    } else {
        u32 w2 = u - 3u * ACT4;
        u32 which = w2 / WT4;
        off = (w2 - which * WT4) * 4u;
        src = which == 0 ? wq : (which == 1 ? wk : wv);
        dst = Wbf + (size_t)which * 589824u + off;
    }
    float4 val = *(const float4*)(src + off);
    ushort4 o;
    o.x = f2bf(val.x); o.y = f2bf(val.y); o.z = f2bf(val.z); o.w = f2bf(val.w);
    *(ushort4*)dst = o;
}

// ---------------- bf16 MFMA GEMM, BK=64 + XOR-swizzled LDS ----------------
// C[m][n] = sum_k A[m][k]*W[n][k] + bias[n].
// 128x128 tile, BK=64, 4 waves (2x2 of 64x64). global_load_lds (16B) with
// LINEAR LDS dest; the XOR swizzle (slot ^= row&7) is applied to the GLOBAL
// source address and to the ds_read address (rule: both-sides-or-neither).
#define GK 768
#define GN 768

static __device__ inline void gload_lds16(const void* g, void* l) {
    __builtin_amdgcn_global_load_lds((const __attribute__((address_space(1))) void*)g,
                                     (__attribute__((address_space(3))) void*)l, 16, 0, 0);
}

__global__ __launch_bounds__(256) void gemm_qkv(
    const u16* __restrict__ Abase, const u16* __restrict__ Wbase,
    const float* __restrict__ bq, const float* __restrict__ bk, const float* __restrict__ bv,
    float* __restrict__ Qf, u16* __restrict__ Qb, u16* __restrict__ Kb, u16* __restrict__ Vb)
{
    const int z = blockIdx.z;
    const u16* A = Abase + (size_t)z * (MROWS * GK);
    const u16* W = Wbase + (size_t)z * (GN * GK);
    const float* bias = (z == 0) ? bq : ((z == 1) ? bk : bv);

    // XCD swizzle: 192 tiles/z, 24 contiguous per XCD (4 A-panels each)
    int id = blockIdx.y * 6 + blockIdx.x;
    int swz = (id & 7) * 24 + (id >> 3);
    const int bm = (swz / 6) * 128, bn = (swz % 6) * 128;

    const int tid = threadIdx.x, wave = tid >> 6, lane = tid & 63;

    __shared__ __align__(16) u16 As[128 * 64];
    __shared__ __align__(16) u16 Bs[128 * 64];

    f32x4 acc[4][4];
#pragma unroll
    for (int i = 0; i < 4; ++i)
#pragma unroll
        for (int j = 0; j < 4; ++j) acc[i][j] = (f32x4){0.f, 0.f, 0.f, 0.f};

    const int wr = (wave >> 1) * 64, wc = (wave & 1) * 64;
    const int r0 = lane & 15, hk = lane >> 4;   // hk in 0..3

    // staging: iter j covers chunk c = j*256 + wave*64 + lane (1024 chunks of 16B)
    int srow[4], scol[4];
#pragma unroll
    for (int j = 0; j < 4; ++j) {
        int c = j * 256 + wave * 64 + lane;
        srow[j] = c >> 3;                         // LDS row (0..127)
        int slot = (c & 7) ^ (srow[j] & 7);       // pre-swizzled source slot
        scol[j] = slot * 8;                       // u16 col in global
    }

    for (int k0 = 0; k0 < GK; k0 += 64) {
#pragma unroll
        for (int j = 0; j < 4; ++j) {
            gload_lds16(A + (size_t)(bm + srow[j]) * GK + k0 + scol[j],
                        As + (size_t)(j * 256 + wave * 64) * 8);
            gload_lds16(W + (size_t)(bn + srow[j]) * GK + k0 + scol[j],
                        Bs + (size_t)(j * 256 + wave * 64) * 8);
        }
        __syncthreads();

        bf16x8 af[2][4], bg[2][4];
#pragma unroll
        for (int kk = 0; kk < 2; ++kk)
#pragma unroll
            for (int f = 0; f < 4; ++f) {
                int ra = wr + f * 16 + r0;
                int sa = (kk * 4 + hk) ^ (ra & 7);
                af[kk][f] = *(const bf16x8*)&As[ra * 64 + sa * 8];
                int rb = wc + f * 16 + r0;
                int sb = (kk * 4 + hk) ^ (rb & 7);
                bg[kk][f] = *(const bf16x8*)&Bs[rb * 64 + sb * 8];
            }
#pragma unroll
        for (int kk = 0; kk < 2; ++kk)
#pragma unroll
            for (int i = 0; i < 4; ++i)
#pragma unroll
                for (int j = 0; j < 4; ++j)
                    acc[i][j] = __builtin_amdgcn_mfma_f32_16x16x32_bf16(af[kk][i], bg[kk][j], acc[i][j], 0, 0, 0);
        __syncthreads();
    }

    // epilogue: C/D layout col=lane&15, row=(lane>>4)*4+reg
    const int cl = lane & 15, rb4 = (lane >> 4) * 4;
    if (z == 0) {
#pragma unroll
        for (int i = 0; i < 4; ++i)
#pragma unroll
            for (int j = 0; j < 4; ++j) {
                int col = bn + wc + j * 16 + cl;
                float b_ = bias[col];
#pragma unroll
                for (int r = 0; r < 4; ++r) {
                    int row = bm + wr + i * 16 + rb4 + r;
                    float vv = acc[i][j][r] + b_;
                    Qf[(size_t)row * GN + col] = vv;
                    Qb[(size_t)row * GN + col] = f2bf(vv);
                }
            }
    } else {
        u16* Ob = (z == 1) ? Kb : Vb;
#pragma unroll
        for (int i = 0; i < 4; ++i)
#pragma unroll
            for (int j = 0; j < 4; ++j) {
                int col = bn + wc + j * 16 + cl;
                float b_ = bias[col];
#pragma unroll
                for (int r = 0; r < 4; ++r) {
                    int row = bm + wr + i * 16 + rb4 + r;
                    Ob[(size_t)row * GN + col] = f2bf(acc[i][j][r] + b_);
                }
            }
    }
}

// ---------------- Vsum[b][e] = sum_s V[b,s,e] (bf16 V) ----------------
__global__ __launch_bounds__(256) void vsum_kernel(const u16* __restrict__ Vb, float* __restrict__ Vsum)
{
    const int b = blockIdx.y;
    const int l = threadIdx.x & 63, sg = threadIdx.x >> 6;
    const int e = blockIdx.x * 64 + l;
    float s = 0.f;
    const u16* p = Vb + ((size_t)b * SEQ + sg * 256) * EMB + e;
    for (int r = 0; r < 256; ++r) s += bf2f(p[(size_t)r * EMB]);
    __shared__ float red[4][64];
    red[sg][l] = s;
    __syncthreads();
    if (sg == 0) Vsum[b * EMB + e] = red[0][l] + red[1][l] + red[2][l] + red[3][l];
}

// ---------------- MFMA local attention (bf16 inputs) ----------------
// Q,K fragments loaded as 16B ushort8 direct from global; LDS only for V^T
// and the P relayout. One wave per block.
__global__ __launch_bounds__(64) void attn_mfma(
    const u16* __restrict__ Qb, const u16* __restrict__ Kb, const u16* __restrict__ Vb,
    const float* __restrict__ Vsum, const float* __restrict__ am, const float* __restrict__ ww,
    float* __restrict__ ctx)
{
    // XCD swizzle: 1536 blocks, 192 contiguous per XCD (= 6 full (b,h) K/V slices)
    int id = blockIdx.x + 32 * (blockIdx.y + 12 * blockIdx.z);
    int swz = (id & 7) * 192 + (id >> 3);
    const int qt = swz & 31, h = (swz >> 5) % 12, b = swz / 384;

    const int q0 = qt * QB;
    int kstart = q0 - WIN;
    if (kstart < 0) kstart = 0;
    if (kstart > SEQ - KB) kstart = SEQ - KB;
    const int lane = threadIdx.x;
    const int fr = lane & 15, kof = (lane >> 4) * 8;
    const int rowg = (lane >> 4) * 4;

    __shared__ __align__(16) u16 Vt[KB][72];   // Vt[d][k]
    __shared__ __align__(16) u16 Ps[QB][72];

    const float w0 = ww[0], w1 = ww[1], w2 = ww[2];

    // ---- Q,K fragments direct from global (bf16) ----
    bf16x8 aq[2][2], bk4[4][2];
    {
        const u16* qb = Qb + ((size_t)(b * SEQ + q0)) * EMB + h * HD;
#pragma unroll
        for (int mi = 0; mi < 2; ++mi)
#pragma unroll
            for (int kk = 0; kk < 2; ++kk)
                aq[mi][kk] = *(const bf16x8*)(qb + (size_t)(mi * 16 + fr) * EMB + kk * 32 + kof);
        const u16* kb = Kb + ((size_t)(b * SEQ + kstart)) * EMB + h * HD;
#pragma unroll
        for (int nj = 0; nj < 4; ++nj)
#pragma unroll
            for (int kk = 0; kk < 2; ++kk)
                bk4[nj][kk] = *(const bf16x8*)(kb + (size_t)(nj * 16 + fr) * EMB + kk * 32 + kof);
    }

    // ---- stage V^T from bf16 ----
    {
        const u16* vbase = Vb + ((size_t)(b * SEQ + kstart)) * EMB + h * HD;
#pragma unroll
        for (int it = 0; it < 8; ++it) {
            int idx = it * 64 + lane;
            int row = idx >> 3, c8 = (idx & 7) * 8;
            bf16x8 vv = *(const bf16x8*)(vbase + (size_t)row * EMB + c8);
#pragma unroll
            for (int jj = 0; jj < 8; ++jj) Vt[c8 + jj][row] = (u16)vv[jj];
        }
    }

    // ---- QK^T: 32x64 over K=64 (registers only) ----
    f32x4 sc[2][4];
#pragma unroll
    for (int i = 0; i < 2; ++i)
#pragma unroll
        for (int j = 0; j < 4; ++j) sc[i][j] = (f32x4){0.f, 0.f, 0.f, 0.f};
#pragma unroll
    for (int kk = 0; kk < 2; ++kk)
#pragma unroll
        for (int mi = 0; mi < 2; ++mi)
#pragma unroll
            for (int nj = 0; nj < 4; ++nj)
                sc[mi][nj] = __builtin_amdgcn_mfma_f32_16x16x32_bf16(aq[mi][kk], bk4[nj][kk], sc[mi][nj], 0, 0, 0);

    // ---- per-row softmax over band + analytic uniform tail ----
    float amv[4];
#pragma unroll
    for (int nj = 0; nj < 4; ++nj) amv[nj] = am[b * SEQ + kstart + nj * 16 + fr];

    float t[2][4][4], cj[2][4][4], ua[2][4];
#pragma unroll
    for (int mi = 0; mi < 2; ++mi)
#pragma unroll
        for (int nj = 0; nj < 4; ++nj)
#pragma unroll
            for (int r = 0; r < 4; ++r) {
                int qrow = q0 + mi * 16 + rowg + r;
                int kcol = kstart + nj * 16 + fr;
                int d = qrow - kcol; if (d < 0) d = -d;
                t[mi][nj][r] = (d <= WIN) ? sc[mi][nj][r] * 0.125f * amv[nj] : 0.f;
                cj[mi][nj][r] = 0.f;
            }
#pragma unroll
    for (int mi = 0; mi < 2; ++mi)
#pragma unroll
        for (int r = 0; r < 4; ++r) ua[mi][r] = 0.f;

#pragma unroll
    for (int it = 0; it < 3; ++it) {
        float wwi = it == 0 ? w0 : (it == 1 ? w1 : w2);
#pragma unroll
        for (int mi = 0; mi < 2; ++mi)
#pragma unroll
            for (int r = 0; r < 4; ++r) {
                float m = 0.f;   // out-of-tile zeros always present
#pragma unroll
                for (int nj = 0; nj < 4; ++nj) m = fmaxf(m, t[mi][nj][r]);
#pragma unroll
                for (int o = 1; o < 16; o <<= 1) m = fmaxf(m, __shfl_xor(m, o, 64));
                float e4[4], s = 0.f;
#pragma unroll
                for (int nj = 0; nj < 4; ++nj) { e4[nj] = __expf(t[mi][nj][r] - m); s += e4[nj]; }
#pragma unroll
                for (int o = 1; o < 16; o <<= 1) s += __shfl_xor(s, o, 64);
                float un = __expf(-m);
                s += (float)(SEQ - KB) * un;
                float inv = wwi / s;
#pragma unroll
                for (int nj = 0; nj < 4; ++nj) cj[mi][nj][r] += e4[nj] * inv;
                ua[mi][r] += un * inv;
            }
        if (it < 2) {
#pragma unroll
            for (int mi = 0; mi < 2; ++mi)
#pragma unroll
                for (int nj = 0; nj < 4; ++nj)
#pragma unroll
                    for (int r = 0; r < 4; ++r) t[mi][nj][r] *= amv[nj];
        }
    }

    // ---- P' = cj - u -> LDS (relayout to A-fragment) ----
#pragma unroll
    for (int mi = 0; mi < 2; ++mi)
#pragma unroll
        for (int nj = 0; nj < 4; ++nj)
#pragma unroll
            for (int r = 0; r < 4; ++r)
                Ps[mi * 16 + rowg + r][nj * 16 + fr] = f2bf(cj[mi][nj][r] - ua[mi][r]);
    __syncthreads();

    // ---- PV: context = P' @ V (+ u * Vsum) ----
    f32x4 pv[2][4];
#pragma unroll
    for (int i = 0; i < 2; ++i)
#pragma unroll
        for (int j = 0; j < 4; ++j) pv[i][j] = (f32x4){0.f, 0.f, 0.f, 0.f};
#pragma unroll
    for (int kk = 0; kk < 2; ++kk) {
        bf16x8 ap[2], bv4[4];
#pragma unroll
        for (int mi = 0; mi < 2; ++mi) ap[mi] = *(const bf16x8*)&Ps[mi * 16 + fr][kk * 32 + kof];
#pragma unroll
        for (int nj = 0; nj < 4; ++nj) bv4[nj] = *(const bf16x8*)&Vt[nj * 16 + fr][kk * 32 + kof];
#pragma unroll
        for (int mi = 0; mi < 2; ++mi)
#pragma unroll
            for (int nj = 0; nj < 4; ++nj)
                pv[mi][nj] = __builtin_amdgcn_mfma_f32_16x16x32_bf16(ap[mi], bv4[nj], pv[mi][nj], 0, 0, 0);
    }

    float vs[4];
#pragma unroll
    for (int nj = 0; nj < 4; ++nj) vs[nj] = Vsum[b * EMB + h * HD + nj * 16 + fr];
#pragma unroll
    for (int mi = 0; mi < 2; ++mi)
#pragma unroll
        for (int nj = 0; nj < 4; ++nj)
#pragma unroll
            for (int r = 0; r < 4; ++r) {
                int row = q0 + mi * 16 + rowg + r;
                ctx[((size_t)(b * SEQ + row)) * EMB + h * HD + nj * 16 + fr] =
                    pv[mi][nj][r] + ua[mi][r] * vs[nj];
            }
}

// ---------------- residual + layernorm ----------------
__global__ __launch_bounds__(256) void ln_kernel(
    const float* __restrict__ Qf, const float* __restrict__ ctxb,
    const float* __restrict__ gamma, const float* __restrict__ beta, float* __restrict__ out)
{
    const int row = blockIdx.x * 4 + (threadIdx.x >> 6);
    const int lane = threadIdx.x & 63;
    const float* qr = Qf + (size_t)row * EMB;
    const float* cr = ctxb + (size_t)row * EMB;
    float x[12];
    float s1 = 0.f, s2 = 0.f;
#pragma unroll
    for (int j = 0; j < 3; ++j) {
        int e0 = j * 256 + lane * 4;
        float4 a = *(const float4*)(qr + e0);
        float4 c = *(const float4*)(cr + e0);
        float4 xx = {a.x + c.x, a.y + c.y, a.z + c.z, a.w + c.w};
        x[j * 4 + 0] = xx.x; x[j * 4 + 1] = xx.y; x[j * 4 + 2] = xx.z; x[j * 4 + 3] = xx.w;
        s1 += xx.x + xx.y + xx.z + xx.w;
        s2 += xx.x * xx.x + xx.y * xx.y + xx.z * xx.z + xx.w * xx.w;
    }
#pragma unroll
    for (int o = 32; o; o >>= 1) { s1 += __shfl_xor(s1, o, 64); s2 += __shfl_xor(s2, o, 64); }
    float mean = s1 * (1.f / EMB);
    float var = s2 * (1.f / EMB) - mean * mean;
    float rstd = rsqrtf(var + LN_EPS);
    float* orow = out + (size_t)row * EMB;
#pragma unroll
    for (int j = 0; j < 3; ++j) {
        int e0 = j * 256 + lane * 4;
        float4 g = *(const float4*)(gamma + e0);
        float4 be = *(const float4*)(beta + e0);
        float4 o;
        o.x = g.x * (x[j * 4 + 0] - mean) * rstd + be.x;
        o.y = g.y * (x[j * 4 + 1] - mean) * rstd + be.y;
        o.z = g.z * (x[j * 4 + 2] - mean) * rstd + be.z;
        o.w = g.w * (x[j * 4 + 3] - mean) * rstd + be.w;
        *(float4*)(orow + e0) = o;
    }
}

// ---------------- launch ----------------
extern "C" void kernel_launch(void* const* d_in, const int* in_sizes, int n_in,
                              void* d_out, int out_size, void* d_ws, size_t ws_size,
                              hipStream_t stream)
{
    const float* q     = (const float*)d_in[0];
    const float* k     = (const float*)d_in[1];
    const float* v     = (const float*)d_in[2];
    const float* amask = (const float*)d_in[3];
    const float* Wq    = (const float*)d_in[4];
    const float* bq    = (const float*)d_in[5];
    const float* Wk    = (const float*)d_in[6];
    const float* bk    = (const float*)d_in[7];
    const float* Wv    = (const float*)d_in[8];
    const float* bv    = (const float*)d_in[9];
    const float* ww    = (const float*)d_in[10];
    const float* gamma = (const float*)d_in[11];
    const float* beta  = (const float*)d_in[12];
    float* out = (float*)d_out;

    char* ws = (char*)d_ws;
    float* ctx  = (float*)(ws);                  // 12,582,912 B
    float* Qf   = (float*)(ws + 16777216);       // 12,582,912 B
    u16*   Qbf  = (u16*)(ws + 33554432);         //  6,291,456 B
    u16*   Kbf  = (u16*)(ws + 41943040);         //  6,291,456 B
    u16*   Vbf  = (u16*)(ws + 50331648);         //  6,291,456 B
    u16*   Abf  = (u16*)(ws + 58720256);         // 18,874,368 B (cast A)
    u16*   Wbf  = (u16*)(ws + 77594624);         //  3,538,944 B (cast W)
    float* Vsum = (float*)(ws + 81133568);       // 12,288 B

    hipLaunchKernelGGL(cast_all, dim3(10944), dim3(256), 0, stream,
                       q, k, v, Wq, Wk, Wv, Abf, Wbf);
    hipLaunchKernelGGL(gemm_qkv, dim3(GN / 128, MROWS / 128, 3), dim3(256), 0, stream,
                       Abf, Wbf, bq, bk, bv, Qf, Qbf, Kbf, Vbf);
    hipLaunchKernelGGL(vsum_kernel, dim3(EMB / 64, NBAT), dim3(256), 0, stream,
                       Vbf, Vsum);
    hipLaunchKernelGGL(attn_mfma, dim3(SEQ / QB, NHEAD, NBAT), dim3(64), 0, stream,
                       Qbf, Kbf, Vbf, Vsum, amask, ww, ctx);
    hipLaunchKernelGGL(ln_kernel, dim3(MROWS / 4), dim3(256), 0, stream,
                       Qf, ctx, gamma, beta, out);
}

// Round 5
// 66.976 us; speedup vs baseline: 2.5146x; 1.2485x over previous
//
#include <hip/hip_runtime.h>
#include <hip/hip_bf16.h>

#define EMB   768
#define SEQ   1024
#define NBAT  4
#define MROWS 4096      // NBAT*SEQ
#define NHEAD 12
#define HD    64
#define WIN   16
#define QB    16
#define KB    64
#define LN_EPS 1e-5f

typedef __attribute__((ext_vector_type(8))) short bf16x8;
typedef __attribute__((ext_vector_type(4))) float f32x4;
typedef unsigned short u16;
typedef unsigned int   u32;

// ---------------- f32 <-> bf16 helpers ----------------
static __device__ inline u16 f2bf(float f) {
    union { float f; u32 u; } a; a.f = f;
    u32 u = a.u;
    u32 r = (u + 0x7fffu + ((u >> 16) & 1u)) >> 16;
    return (u16)r;
}
static __device__ inline float bf2f(u16 x) {
    union { u32 u; float f; } c; c.u = ((u32)x) << 16; return c.f;
}

// ---------------- cast f32 -> bf16 (activations + weights) ----------------
#define ACT4 786432u    // 4096*768/4
#define WT4  147456u    // 768*768/4
__global__ __launch_bounds__(256) void cast_all(
    const float* __restrict__ q, const float* __restrict__ k, const float* __restrict__ v,
    const float* __restrict__ wq, const float* __restrict__ wk, const float* __restrict__ wv,
    u16* __restrict__ Abf, u16* __restrict__ Wbf)
{
    u32 u = blockIdx.x * 256u + threadIdx.x;
    const float* src; u16* dst; u32 off;
    if (u < 3u * ACT4) {
        u32 which = u / ACT4;
        off = (u - which * ACT4) * 4u;
        src = which == 0 ? q : (which == 1 ? k : v);
        dst = Abf + (size_t)which * 3145728u + off;
    } else {
        u32 w2 = u - 3u * ACT4;
        u32 which = w2 / WT4;
        off = (w2 - which * WT4) * 4u;
        src = which == 0 ? wq : (which == 1 ? wk : wv);
        dst = Wbf + (size_t)which * 589824u + off;
    }
    float4 val = *(const float4*)(src + off);
    ushort4 o;
    o.x = f2bf(val.x); o.y = f2bf(val.y); o.z = f2bf(val.z); o.w = f2bf(val.w);
    *(ushort4*)dst = o;
}

// ---------------- bf16 MFMA GEMM: 64x128 tile, BK=64, XOR-swizzled LDS ----------------
// C[m][n] = sum_k A[m][k]*W[n][k] + bias[n]; outputs bf16 only.
// 1152 blocks (4.5/CU). global_load_lds 16B with linear LDS dest; XOR swizzle
// (slot ^= row&7) applied to the GLOBAL source and the ds_read address.
#define GK 768
#define GN 768

static __device__ inline void gload_lds16(const void* g, void* l) {
    __builtin_amdgcn_global_load_lds((const __attribute__((address_space(1))) void*)g,
                                     (__attribute__((address_space(3))) void*)l, 16, 0, 0);
}

__global__ __launch_bounds__(256) void gemm_qkv(
    const u16* __restrict__ Abase, const u16* __restrict__ Wbase,
    const float* __restrict__ bq, const float* __restrict__ bk, const float* __restrict__ bv,
    u16* __restrict__ Qb, u16* __restrict__ Kb, u16* __restrict__ Vb)
{
    const int z = blockIdx.z;
    const u16* A = Abase + (size_t)z * (MROWS * GK);
    const u16* W = Wbase + (size_t)z * (GN * GK);
    const float* bias = (z == 0) ? bq : ((z == 1) ? bk : bv);
    u16* Ob = (z == 0) ? Qb : ((z == 1) ? Kb : Vb);

    // XCD swizzle: 384 tiles/z, 48 contiguous per XCD (8 A-panels each)
    int id = blockIdx.y * 6 + blockIdx.x;
    int swz = (id & 7) * 48 + (id >> 3);
    const int bm = (swz / 6) * 64, bn = (swz % 6) * 128;

    const int tid = threadIdx.x, wave = tid >> 6, lane = tid & 63;

    __shared__ __align__(16) u16 As[64 * 64];
    __shared__ __align__(16) u16 Bs[128 * 64];

    f32x4 acc[2][4];
#pragma unroll
    for (int i = 0; i < 2; ++i)
#pragma unroll
        for (int j = 0; j < 4; ++j) acc[i][j] = (f32x4){0.f, 0.f, 0.f, 0.f};

    const int wr = (wave >> 1) * 32, wc = (wave & 1) * 64;
    const int r0 = lane & 15, hk = lane >> 4;

    // staging indices: chunk c -> row = c>>3, src slot = (c&7)^(row&7)
    int arow[2], acol[2], brow[4], bcol[4];
#pragma unroll
    for (int j = 0; j < 2; ++j) {
        int c = j * 256 + tid;
        arow[j] = c >> 3;
        acol[j] = ((c & 7) ^ (arow[j] & 7)) * 8;
    }
#pragma unroll
    for (int j = 0; j < 4; ++j) {
        int c = j * 256 + tid;
        brow[j] = c >> 3;
        bcol[j] = ((c & 7) ^ (brow[j] & 7)) * 8;
    }

    for (int k0 = 0; k0 < GK; k0 += 64) {
#pragma unroll
        for (int j = 0; j < 2; ++j)
            gload_lds16(A + (size_t)(bm + arow[j]) * GK + k0 + acol[j],
                        As + (size_t)(j * 256 + wave * 64) * 8);
#pragma unroll
        for (int j = 0; j < 4; ++j)
            gload_lds16(W + (size_t)(bn + brow[j]) * GK + k0 + bcol[j],
                        Bs + (size_t)(j * 256 + wave * 64) * 8);
        __syncthreads();

        bf16x8 af[2][2], bg[2][4];
#pragma unroll
        for (int kk = 0; kk < 2; ++kk) {
#pragma unroll
            for (int i = 0; i < 2; ++i) {
                int ra = wr + i * 16 + r0;
                int sa = (kk * 4 + hk) ^ (ra & 7);
                af[kk][i] = *(const bf16x8*)&As[ra * 64 + sa * 8];
            }
#pragma unroll
            for (int j = 0; j < 4; ++j) {
                int rb = wc + j * 16 + r0;
                int sb = (kk * 4 + hk) ^ (rb & 7);
                bg[kk][j] = *(const bf16x8*)&Bs[rb * 64 + sb * 8];
            }
        }
#pragma unroll
        for (int kk = 0; kk < 2; ++kk)
#pragma unroll
            for (int i = 0; i < 2; ++i)
#pragma unroll
                for (int j = 0; j < 4; ++j)
                    acc[i][j] = __builtin_amdgcn_mfma_f32_16x16x32_bf16(af[kk][i], bg[kk][j], acc[i][j], 0, 0, 0);
        __syncthreads();
    }

    // epilogue: C/D layout col=lane&15, row=(lane>>4)*4+reg
    const int cl = lane & 15, rb4 = (lane >> 4) * 4;
#pragma unroll
    for (int i = 0; i < 2; ++i)
#pragma unroll
        for (int j = 0; j < 4; ++j) {
            int col = bn + wc + j * 16 + cl;
            float b_ = bias[col];
#pragma unroll
            for (int r = 0; r < 4; ++r) {
                int row = bm + wr + i * 16 + rb4 + r;
                Ob[(size_t)row * GN + col] = f2bf(acc[i][j][r] + b_);
            }
        }
}

// ---------------- Vsum[b][e] = sum_s V[b,s,e] (bf16 V) ----------------
__global__ __launch_bounds__(256) void vsum_kernel(const u16* __restrict__ Vb, float* __restrict__ Vsum)
{
    const int b = blockIdx.y;
    const int l = threadIdx.x & 63, sg = threadIdx.x >> 6;
    const int e = blockIdx.x * 64 + l;
    float s = 0.f;
    const u16* p = Vb + ((size_t)b * SEQ + sg * 256) * EMB + e;
    for (int r = 0; r < 256; ++r) s += bf2f(p[(size_t)r * EMB]);
    __shared__ float red[4][64];
    red[sg][l] = s;
    __syncthreads();
    if (sg == 0) Vsum[b * EMB + e] = red[0][l] + red[1][l] + red[2][l] + red[3][l];
}

// ---------------- fused MFMA local attention + residual + layernorm ----------------
// One block = (b, 16-query tile), 12 waves = 12 heads. Per wave: QK^T (MFMA),
// 3-window softmax in-register (+analytic uniform tail), P relayout via LDS
// (same-wave DS ordering, no barrier), PV (MFMA, V-frags gathered from L2),
// then cross-wave LN reduction (2 barriers) and f32 output store.
__global__ __launch_bounds__(768, 3) void attn_ln(
    const u16* __restrict__ Qb, const u16* __restrict__ Kb, const u16* __restrict__ Vb,
    const float* __restrict__ Vsum, const float* __restrict__ am, const float* __restrict__ ww,
    const float* __restrict__ gamma, const float* __restrict__ beta, float* __restrict__ out)
{
    // XCD swizzle over 256 blocks: 32 contiguous per XCD
    int id = blockIdx.x + 64 * blockIdx.y;
    int swz = (id & 7) * 32 + (id >> 3);
    const int qt = swz & 63, b = swz >> 6;

    const int q0 = qt * QB;
    int kstart = q0 - WIN;
    if (kstart < 0) kstart = 0;
    if (kstart > SEQ - KB) kstart = SEQ - KB;

    const int h = threadIdx.x >> 6, lane = threadIdx.x & 63;
    const int fr = lane & 15, hk = lane >> 4;
    const int kof = hk * 8, rowg = hk * 4;

    __shared__ __align__(16) u16 Ps[NHEAD][QB][68];
    __shared__ float ps1[QB][13], ps2[QB][13];
    __shared__ float mu[QB], rs[QB];

    const float w0 = ww[0], w1 = ww[1], w2 = ww[2];

    // ---- fragments direct from global (bf16, L2-resident) ----
    bf16x8 aq[2], bk4[4][2], bv4[4][2];
    {
        const u16* qb = Qb + ((size_t)(b * SEQ + q0)) * EMB + h * HD;
#pragma unroll
        for (int kk = 0; kk < 2; ++kk)
            aq[kk] = *(const bf16x8*)(qb + (size_t)fr * EMB + kk * 32 + kof);
        const u16* kb = Kb + ((size_t)(b * SEQ + kstart)) * EMB + h * HD;
#pragma unroll
        for (int nj = 0; nj < 4; ++nj)
#pragma unroll
            for (int kk = 0; kk < 2; ++kk)
                bk4[nj][kk] = *(const bf16x8*)(kb + (size_t)(nj * 16 + fr) * EMB + kk * 32 + kof);
        // V^T gather: bv4[nj][kk][j] = V[kstart + kk*32+kof+j][h*64 + nj*16+fr]
        const u16* vb = Vb + ((size_t)(b * SEQ + kstart)) * EMB + h * HD;
#pragma unroll
        for (int nj = 0; nj < 4; ++nj)
#pragma unroll
            for (int kk = 0; kk < 2; ++kk) {
                union { bf16x8 v; u16 s[8]; } tmp;
#pragma unroll
                for (int j = 0; j < 8; ++j)
                    tmp.s[j] = vb[(size_t)(kk * 32 + kof + j) * EMB + nj * 16 + fr];
                bv4[nj][kk] = tmp.v;
            }
    }

    // ---- QK^T: 16x64 over K=64 ----
    f32x4 sc[4];
#pragma unroll
    for (int j = 0; j < 4; ++j) sc[j] = (f32x4){0.f, 0.f, 0.f, 0.f};
#pragma unroll
    for (int kk = 0; kk < 2; ++kk)
#pragma unroll
        for (int nj = 0; nj < 4; ++nj)
            sc[nj] = __builtin_amdgcn_mfma_f32_16x16x32_bf16(aq[kk], bk4[nj][kk], sc[nj], 0, 0, 0);

    // ---- per-row softmax over band + analytic uniform tail ----
    float amv[4];
#pragma unroll
    for (int nj = 0; nj < 4; ++nj) amv[nj] = am[b * SEQ + kstart + nj * 16 + fr];

    float t[4][4], cj[4][4], ua[4];
#pragma unroll
    for (int nj = 0; nj < 4; ++nj)
#pragma unroll
        for (int r = 0; r < 4; ++r) {
            int qrow = q0 + rowg + r;
            int kcol = kstart + nj * 16 + fr;
            int d = qrow - kcol; if (d < 0) d = -d;
            t[nj][r] = (d <= WIN) ? sc[nj][r] * 0.125f * amv[nj] : 0.f;
            cj[nj][r] = 0.f;
        }
#pragma unroll
    for (int r = 0; r < 4; ++r) ua[r] = 0.f;

#pragma unroll
    for (int it = 0; it < 3; ++it) {
        float wwi = it == 0 ? w0 : (it == 1 ? w1 : w2);
#pragma unroll
        for (int r = 0; r < 4; ++r) {
            float m = 0.f;   // out-of-tile zeros always present (SEQ > KB)
#pragma unroll
            for (int nj = 0; nj < 4; ++nj) m = fmaxf(m, t[nj][r]);
#pragma unroll
            for (int o = 1; o < 16; o <<= 1) m = fmaxf(m, __shfl_xor(m, o, 64));
            float e4[4], s = 0.f;
#pragma unroll
            for (int nj = 0; nj < 4; ++nj) { e4[nj] = __expf(t[nj][r] - m); s += e4[nj]; }
#pragma unroll
            for (int o = 1; o < 16; o <<= 1) s += __shfl_xor(s, o, 64);
            float un = __expf(-m);
            s += (float)(SEQ - KB) * un;
            float inv = wwi / s;
#pragma unroll
            for (int nj = 0; nj < 4; ++nj) cj[nj][r] += e4[nj] * inv;
            ua[r] += un * inv;
        }
        if (it < 2) {
#pragma unroll
            for (int nj = 0; nj < 4; ++nj)
#pragma unroll
                for (int r = 0; r < 4; ++r) t[nj][r] *= amv[nj];
        }
    }

    // ---- P' = cj - u -> LDS relayout (same-wave write->read, no barrier) ----
#pragma unroll
    for (int nj = 0; nj < 4; ++nj)
#pragma unroll
        for (int r = 0; r < 4; ++r)
            Ps[h][rowg + r][nj * 16 + fr] = f2bf(cj[nj][r] - ua[r]);

    // ---- PV: ctx = P' @ V (+ u * Vsum) ----
    f32x4 pv[4];
#pragma unroll
    for (int j = 0; j < 4; ++j) pv[j] = (f32x4){0.f, 0.f, 0.f, 0.f};
#pragma unroll
    for (int kk = 0; kk < 2; ++kk) {
        bf16x8 ap = *(const bf16x8*)&Ps[h][fr][kk * 32 + kof];
#pragma unroll
        for (int nj = 0; nj < 4; ++nj)
            pv[nj] = __builtin_amdgcn_mfma_f32_16x16x32_bf16(ap, bv4[nj][kk], pv[nj], 0, 0, 0);
    }

    // ---- x = residual(q) + ctx ----
    float vs[4];
#pragma unroll
    for (int nj = 0; nj < 4; ++nj) vs[nj] = Vsum[b * EMB + h * HD + nj * 16 + fr];

    float xv[4][4];
#pragma unroll
    for (int nj = 0; nj < 4; ++nj)
#pragma unroll
        for (int r = 0; r < 4; ++r) {
            int row = q0 + rowg + r;
            float qres = bf2f(Qb[((size_t)(b * SEQ + row)) * EMB + h * HD + nj * 16 + fr]);
            xv[nj][r] = qres + pv[nj][r] + ua[r] * vs[nj];
        }

    // ---- LN: per-head partial sums -> cross-wave reduce -> apply ----
    float s1r[4], s2r[4];
#pragma unroll
    for (int r = 0; r < 4; ++r) {
        float a = 0.f, c = 0.f;
#pragma unroll
        for (int nj = 0; nj < 4; ++nj) { a += xv[nj][r]; c += xv[nj][r] * xv[nj][r]; }
#pragma unroll
        for (int o = 1; o < 16; o <<= 1) { a += __shfl_xor(a, o, 64); c += __shfl_xor(c, o, 64); }
        s1r[r] = a; s2r[r] = c;
    }
    if (fr == 0) {
#pragma unroll
        for (int r = 0; r < 4; ++r) { ps1[rowg + r][h] = s1r[r]; ps2[rowg + r][h] = s2r[r]; }
    }
    __syncthreads();
    if (h == 0 && lane < QB) {
        float a = 0.f, c = 0.f;
#pragma unroll
        for (int w = 0; w < NHEAD; ++w) { a += ps1[lane][w]; c += ps2[lane][w]; }
        float mean = a * (1.f / EMB);
        float var = c * (1.f / EMB) - mean * mean;
        mu[lane] = mean;
        rs[lane] = rsqrtf(var + LN_EPS);
    }
    __syncthreads();

#pragma unroll
    for (int nj = 0; nj < 4; ++nj) {
        int col = h * HD + nj * 16 + fr;
        float g = gamma[col], be = beta[col];
#pragma unroll
        for (int r = 0; r < 4; ++r) {
            int row = q0 + rowg + r;
            out[((size_t)(b * SEQ + row)) * EMB + col] =
                g * (xv[nj][r] - mu[rowg + r]) * rs[rowg + r] + be;
        }
    }
}

// ---------------- launch ----------------
extern "C" void kernel_launch(void* const* d_in, const int* in_sizes, int n_in,
                              void* d_out, int out_size, void* d_ws, size_t ws_size,
                              hipStream_t stream)
{
    const float* q     = (const float*)d_in[0];
    const float* k     = (const float*)d_in[1];
    const float* v     = (const float*)d_in[2];
    const float* amask = (const float*)d_in[3];
    const float* Wq    = (const float*)d_in[4];
    const float* bq    = (const float*)d_in[5];
    const float* Wk    = (const float*)d_in[6];
    const float* bk    = (const float*)d_in[7];
    const float* Wv    = (const float*)d_in[8];
    const float* bv    = (const float*)d_in[9];
    const float* ww    = (const float*)d_in[10];
    const float* gamma = (const float*)d_in[11];
    const float* beta  = (const float*)d_in[12];
    float* out = (float*)d_out;

    char* ws = (char*)d_ws;
    u16*   Abf  = (u16*)(ws);                    // 18,874,368 B
    u16*   Wbf  = (u16*)(ws + 18874368);         //  3,538,944 B
    u16*   Qbf  = (u16*)(ws + 22413312);         //  6,291,456 B
    u16*   Kbf  = (u16*)(ws + 28704768);         //  6,291,456 B
    u16*   Vbf  = (u16*)(ws + 34996224);         //  6,291,456 B
    float* Vsum = (float*)(ws + 41287680);       //     12,288 B

    hipLaunchKernelGGL(cast_all, dim3(10944), dim3(256), 0, stream,
                       q, k, v, Wq, Wk, Wv, Abf, Wbf);
    hipLaunchKernelGGL(gemm_qkv, dim3(GN / 128, MROWS / 64, 3), dim3(256), 0, stream,
                       Abf, Wbf, bq, bk, bv, Qbf, Kbf, Vbf);
    hipLaunchKernelGGL(vsum_kernel, dim3(EMB / 64, NBAT), dim3(256), 0, stream,
                       Vbf, Vsum);
    hipLaunchKernelGGL(attn_ln, dim3(SEQ / QB, NBAT), dim3(768), 0, stream,
                       Qbf, Kbf, Vbf, Vsum, amask, ww, gamma, beta, out);
}

// Round 7
// 65.966 us; speedup vs baseline: 2.5531x; 1.0153x over previous
//
#include <hip/hip_runtime.h>
#include <hip/hip_bf16.h>

#define EMB   768
#define SEQ   1024
#define NBAT  4
#define MROWS 4096      // NBAT*SEQ
#define NHEAD 12
#define HD    64
#define WIN   16
#define QB    16
#define KB    64
#define LN_EPS 1e-5f

typedef __attribute__((ext_vector_type(8))) short bf16x8;
typedef __attribute__((ext_vector_type(4))) float f32x4;
typedef unsigned short u16;
typedef unsigned int   u32;

// ---------------- f32 <-> bf16 helpers ----------------
static __device__ inline u16 f2bf(float f) {
    union { float f; u32 u; } a; a.f = f;
    u32 u = a.u;
    u32 r = (u + 0x7fffu + ((u >> 16) & 1u)) >> 16;
    return (u16)r;
}
static __device__ inline float bf2f(u16 x) {
    union { u32 u; float f; } c; c.u = ((u32)x) << 16; return c.f;
}

// ---------------- cast f32 -> bf16 (activations + weights) ----------------
#define ACT4 786432u    // 4096*768/4
#define WT4  147456u    // 768*768/4
__global__ __launch_bounds__(256) void cast_all(
    const float* __restrict__ q, const float* __restrict__ k, const float* __restrict__ v,
    const float* __restrict__ wq, const float* __restrict__ wk, const float* __restrict__ wv,
    u16* __restrict__ Abf, u16* __restrict__ Wbf)
{
    u32 u = blockIdx.x * 256u + threadIdx.x;
    const float* src; u16* dst; u32 off;
    if (u < 3u * ACT4) {
        u32 which = u / ACT4;
        off = (u - which * ACT4) * 4u;
        src = which == 0 ? q : (which == 1 ? k : v);
        dst = Abf + (size_t)which * 3145728u + off;
    } else {
        u32 w2 = u - 3u * ACT4;
        u32 which = w2 / WT4;
        off = (w2 - which * WT4) * 4u;
        src = which == 0 ? wq : (which == 1 ? wk : wv);
        dst = Wbf + (size_t)which * 589824u + off;
    }
    float4 val = *(const float4*)(src + off);
    ushort4 o;
    o.x = f2bf(val.x); o.y = f2bf(val.y); o.z = f2bf(val.z); o.w = f2bf(val.w);
    *(ushort4*)dst = o;
}

// ---------------- bf16 MFMA GEMM: 64x128 tile, BK=64, dbuf + counted vmcnt ----------------
// 2-phase pipeline: issue STAGE(next) before COMPUTE(cur); s_waitcnt vmcnt(6)
// (next tile's 6 loads/wave stay in flight) + raw s_barrier. sched_barrier(0)
// pins after the vmcnt and around each s_barrier so the compiler cannot hoist
// COMPUTE's ds_reads (cross-wave staged data) into the pre-barrier window,
// nor sink STAGE writes across the read-completion barrier. XOR swizzle
// (slot ^= row&7) on the GLOBAL source and the ds_read address; linear LDS dest.
#define GK 768
#define GN 768

static __device__ inline void gload_lds16(const void* g, void* l) {
    __builtin_amdgcn_global_load_lds((const __attribute__((address_space(1))) void*)g,
                                     (__attribute__((address_space(3))) void*)l, 16, 0, 0);
}

__global__ __launch_bounds__(256) void gemm_qkv(
    const u16* __restrict__ Abase, const u16* __restrict__ Wbase,
    const float* __restrict__ bq, const float* __restrict__ bk, const float* __restrict__ bv,
    u16* __restrict__ Qb, u16* __restrict__ Kb, u16* __restrict__ Vb)
{
    const int z = blockIdx.z;
    const u16* A = Abase + (size_t)z * (MROWS * GK);
    const u16* W = Wbase + (size_t)z * (GN * GK);
    const float* bias = (z == 0) ? bq : ((z == 1) ? bk : bv);
    u16* Ob = (z == 0) ? Qb : ((z == 1) ? Kb : Vb);

    // XCD swizzle: 384 tiles/z, 48 contiguous per XCD (8 A-panels each)
    int id = blockIdx.y * 6 + blockIdx.x;
    int swz = (id & 7) * 48 + (id >> 3);
    const int bm = (swz / 6) * 64, bn = (swz % 6) * 128;

    const int tid = threadIdx.x, wave = tid >> 6, lane = tid & 63;

    __shared__ __align__(16) u16 As[2][64 * 64];
    __shared__ __align__(16) u16 Bs[2][128 * 64];

    f32x4 acc[2][4];
#pragma unroll
    for (int i = 0; i < 2; ++i)
#pragma unroll
        for (int j = 0; j < 4; ++j) acc[i][j] = (f32x4){0.f, 0.f, 0.f, 0.f};

    const int wr = (wave >> 1) * 32, wc = (wave & 1) * 64;
    const int r0 = lane & 15, hk = lane >> 4;

    // staging indices: chunk c -> row = c>>3, src slot = (c&7)^(row&7)
    int arow[2], acol[2], brow[4], bcol[4];
#pragma unroll
    for (int j = 0; j < 2; ++j) {
        int c = j * 256 + tid;
        arow[j] = c >> 3;
        acol[j] = ((c & 7) ^ (arow[j] & 7)) * 8;
    }
#pragma unroll
    for (int j = 0; j < 4; ++j) {
        int c = j * 256 + tid;
        brow[j] = c >> 3;
        bcol[j] = ((c & 7) ^ (brow[j] & 7)) * 8;
    }

#define GEMM_STAGE(buf, K0) do { \
    _Pragma("unroll") for (int j = 0; j < 2; ++j) \
        gload_lds16(A + (size_t)(bm + arow[j]) * GK + (K0) + acol[j], \
                    &As[buf][(j * 256 + wave * 64) * 8]); \
    _Pragma("unroll") for (int j = 0; j < 4; ++j) \
        gload_lds16(W + (size_t)(bn + brow[j]) * GK + (K0) + bcol[j], \
                    &Bs[buf][(j * 256 + wave * 64) * 8]); \
} while (0)

#define GEMM_COMPUTE(buf) do { \
    bf16x8 af[2][2], bg[2][4]; \
    _Pragma("unroll") for (int kk = 0; kk < 2; ++kk) { \
        _Pragma("unroll") for (int i = 0; i < 2; ++i) { \
            int ra = wr + i * 16 + r0; int sa = (kk * 4 + hk) ^ (ra & 7); \
            af[kk][i] = *(const bf16x8*)&As[buf][ra * 64 + sa * 8]; } \
        _Pragma("unroll") for (int j = 0; j < 4; ++j) { \
            int rb = wc + j * 16 + r0; int sb = (kk * 4 + hk) ^ (rb & 7); \
            bg[kk][j] = *(const bf16x8*)&Bs[buf][rb * 64 + sb * 8]; } } \
    _Pragma("unroll") for (int kk = 0; kk < 2; ++kk) \
    _Pragma("unroll") for (int i = 0; i < 2; ++i) \
    _Pragma("unroll") for (int j = 0; j < 4; ++j) \
        acc[i][j] = __builtin_amdgcn_mfma_f32_16x16x32_bf16(af[kk][i], bg[kk][j], acc[i][j], 0, 0, 0); \
} while (0)

    GEMM_STAGE(0, 0);
    for (int t = 0; t < 11; ++t) {
        int cur = t & 1;
        GEMM_STAGE(cur ^ 1, (t + 1) * 64);          // issue next tile first
        asm volatile("s_waitcnt vmcnt(6)" ::: "memory");   // cur landed; next in flight
        __builtin_amdgcn_sched_barrier(0);
        __builtin_amdgcn_s_barrier();               // all waves' cur loads landed
        __builtin_amdgcn_sched_barrier(0);
        GEMM_COMPUTE(cur);
        __builtin_amdgcn_sched_barrier(0);
        __builtin_amdgcn_s_barrier();               // all reads of cur done -> safe to overwrite
        __builtin_amdgcn_sched_barrier(0);
    }
    asm volatile("s_waitcnt vmcnt(0)" ::: "memory");
    __builtin_amdgcn_sched_barrier(0);
    __builtin_amdgcn_s_barrier();
    __builtin_amdgcn_sched_barrier(0);
    GEMM_COMPUTE(1);

#undef GEMM_STAGE
#undef GEMM_COMPUTE

    // epilogue: C/D layout col=lane&15, row=(lane>>4)*4+reg
    const int cl = lane & 15, rb4 = (lane >> 4) * 4;
#pragma unroll
    for (int i = 0; i < 2; ++i)
#pragma unroll
        for (int j = 0; j < 4; ++j) {
            int col = bn + wc + j * 16 + cl;
            float b_ = bias[col];
#pragma unroll
            for (int r = 0; r < 4; ++r) {
                int row = bm + wr + i * 16 + rb4 + r;
                Ob[(size_t)row * GN + col] = f2bf(acc[i][j][r] + b_);
            }
        }
}

// ---------------- Vsum[b][e] = sum_s V[b,s,e] (bf16 V) ----------------
__global__ __launch_bounds__(256) void vsum_kernel(const u16* __restrict__ Vb, float* __restrict__ Vsum)
{
    const int b = blockIdx.y;
    const int l = threadIdx.x & 63, sg = threadIdx.x >> 6;
    const int e = blockIdx.x * 64 + l;
    float s = 0.f;
    const u16* p = Vb + ((size_t)b * SEQ + sg * 256) * EMB + e;
    for (int r = 0; r < 256; ++r) s += bf2f(p[(size_t)r * EMB]);
    __shared__ float red[4][64];
    red[sg][l] = s;
    __syncthreads();
    if (sg == 0) Vsum[b * EMB + e] = red[0][l] + red[1][l] + red[2][l] + red[3][l];
}

// ---------------- fused MFMA local attention + residual + layernorm ----------------
// (r5-verbatim passing version) One block = (b, 16-query tile), 12 waves = 12 heads.
__global__ __launch_bounds__(768, 3) void attn_ln(
    const u16* __restrict__ Qb, const u16* __restrict__ Kb, const u16* __restrict__ Vb,
    const float* __restrict__ Vsum, const float* __restrict__ am, const float* __restrict__ ww,
    const float* __restrict__ gamma, const float* __restrict__ beta, float* __restrict__ out)
{
    // XCD swizzle over 256 blocks: 32 contiguous per XCD
    int id = blockIdx.x + 64 * blockIdx.y;
    int swz = (id & 7) * 32 + (id >> 3);
    const int qt = swz & 63, b = swz >> 6;

    const int q0 = qt * QB;
    int kstart = q0 - WIN;
    if (kstart < 0) kstart = 0;
    if (kstart > SEQ - KB) kstart = SEQ - KB;

    const int h = threadIdx.x >> 6, lane = threadIdx.x & 63;
    const int fr = lane & 15, hk = lane >> 4;
    const int kof = hk * 8, rowg = hk * 4;

    __shared__ __align__(16) u16 Ps[NHEAD][QB][68];
    __shared__ float ps1[QB][13], ps2[QB][13];
    __shared__ float mu[QB], rs[QB];

    const float w0 = ww[0], w1 = ww[1], w2 = ww[2];

    // ---- fragments direct from global (bf16, L2-resident) ----
    bf16x8 aq[2], bk4[4][2], bv4[4][2];
    {
        const u16* qb = Qb + ((size_t)(b * SEQ + q0)) * EMB + h * HD;
#pragma unroll
        for (int kk = 0; kk < 2; ++kk)
            aq[kk] = *(const bf16x8*)(qb + (size_t)fr * EMB + kk * 32 + kof);
        const u16* kb = Kb + ((size_t)(b * SEQ + kstart)) * EMB + h * HD;
#pragma unroll
        for (int nj = 0; nj < 4; ++nj)
#pragma unroll
            for (int kk = 0; kk < 2; ++kk)
                bk4[nj][kk] = *(const bf16x8*)(kb + (size_t)(nj * 16 + fr) * EMB + kk * 32 + kof);
        // V^T gather: bv4[nj][kk][j] = V[kstart + kk*32+kof+j][h*64 + nj*16+fr]
        const u16* vb = Vb + ((size_t)(b * SEQ + kstart)) * EMB + h * HD;
#pragma unroll
        for (int nj = 0; nj < 4; ++nj)
#pragma unroll
            for (int kk = 0; kk < 2; ++kk) {
                union { bf16x8 v; u16 s[8]; } tmp;
#pragma unroll
                for (int j = 0; j < 8; ++j)
                    tmp.s[j] = vb[(size_t)(kk * 32 + kof + j) * EMB + nj * 16 + fr];
                bv4[nj][kk] = tmp.v;
            }
    }

    // ---- QK^T: 16x64 over K=64 ----
    f32x4 sc[4];
#pragma unroll
    for (int j = 0; j < 4; ++j) sc[j] = (f32x4){0.f, 0.f, 0.f, 0.f};
#pragma unroll
    for (int kk = 0; kk < 2; ++kk)
#pragma unroll
        for (int nj = 0; nj < 4; ++nj)
            sc[nj] = __builtin_amdgcn_mfma_f32_16x16x32_bf16(aq[kk], bk4[nj][kk], sc[nj], 0, 0, 0);

    // ---- per-row softmax over band + analytic uniform tail ----
    float amv[4];
#pragma unroll
    for (int nj = 0; nj < 4; ++nj) amv[nj] = am[b * SEQ + kstart + nj * 16 + fr];

    float t[4][4], cj[4][4], ua[4];
#pragma unroll
    for (int nj = 0; nj < 4; ++nj)
#pragma unroll
        for (int r = 0; r < 4; ++r) {
            int qrow = q0 + rowg + r;
            int kcol = kstart + nj * 16 + fr;
            int d = qrow - kcol; if (d < 0) d = -d;
            t[nj][r] = (d <= WIN) ? sc[nj][r] * 0.125f * amv[nj] : 0.f;
            cj[nj][r] = 0.f;
        }
#pragma unroll
    for (int r = 0; r < 4; ++r) ua[r] = 0.f;

#pragma unroll
    for (int it = 0; it < 3; ++it) {
        float wwi = it == 0 ? w0 : (it == 1 ? w1 : w2);
#pragma unroll
        for (int r = 0; r < 4; ++r) {
            float m = 0.f;   // out-of-tile zeros always present (SEQ > KB)
#pragma unroll
            for (int nj = 0; nj < 4; ++nj) m = fmaxf(m, t[nj][r]);
#pragma unroll
            for (int o = 1; o < 16; o <<= 1) m = fmaxf(m, __shfl_xor(m, o, 64));
            float e4[4], s = 0.f;
#pragma unroll
            for (int nj = 0; nj < 4; ++nj) { e4[nj] = __expf(t[nj][r] - m); s += e4[nj]; }
#pragma unroll
            for (int o = 1; o < 16; o <<= 1) s += __shfl_xor(s, o, 64);
            float un = __expf(-m);
            s += (float)(SEQ - KB) * un;
            float inv = wwi / s;
#pragma unroll
            for (int nj = 0; nj < 4; ++nj) cj[nj][r] += e4[nj] * inv;
            ua[r] += un * inv;
        }
        if (it < 2) {
#pragma unroll
            for (int nj = 0; nj < 4; ++nj)
#pragma unroll
                for (int r = 0; r < 4; ++r) t[nj][r] *= amv[nj];
        }
    }

    // ---- P' = cj - u -> LDS relayout (same-wave write->read, no barrier) ----
#pragma unroll
    for (int nj = 0; nj < 4; ++nj)
#pragma unroll
        for (int r = 0; r < 4; ++r)
            Ps[h][rowg + r][nj * 16 + fr] = f2bf(cj[nj][r] - ua[r]);

    // ---- PV: ctx = P' @ V (+ u * Vsum) ----
    f32x4 pv[4];
#pragma unroll
    for (int j = 0; j < 4; ++j) pv[j] = (f32x4){0.f, 0.f, 0.f, 0.f};
#pragma unroll
    for (int kk = 0; kk < 2; ++kk) {
        bf16x8 ap = *(const bf16x8*)&Ps[h][fr][kk * 32 + kof];
#pragma unroll
        for (int nj = 0; nj < 4; ++nj)
            pv[nj] = __builtin_amdgcn_mfma_f32_16x16x32_bf16(ap, bv4[nj][kk], pv[nj], 0, 0, 0);
    }

    // ---- x = residual(q) + ctx ----
    float vs[4];
#pragma unroll
    for (int nj = 0; nj < 4; ++nj) vs[nj] = Vsum[b * EMB + h * HD + nj * 16 + fr];

    float xv[4][4];
#pragma unroll
    for (int nj = 0; nj < 4; ++nj)
#pragma unroll
        for (int r = 0; r < 4; ++r) {
            int row = q0 + rowg + r;
            float qres = bf2f(Qb[((size_t)(b * SEQ + row)) * EMB + h * HD + nj * 16 + fr]);
            xv[nj][r] = qres + pv[nj][r] + ua[r] * vs[nj];
        }

    // ---- LN: per-head partial sums -> cross-wave reduce -> apply ----
    float s1r[4], s2r[4];
#pragma unroll
    for (int r = 0; r < 4; ++r) {
        float a = 0.f, c = 0.f;
#pragma unroll
        for (int nj = 0; nj < 4; ++nj) { a += xv[nj][r]; c += xv[nj][r] * xv[nj][r]; }
#pragma unroll
        for (int o = 1; o < 16; o <<= 1) { a += __shfl_xor(a, o, 64); c += __shfl_xor(c, o, 64); }
        s1r[r] = a; s2r[r] = c;
    }
    if (fr == 0) {
#pragma unroll
        for (int r = 0; r < 4; ++r) { ps1[rowg + r][h] = s1r[r]; ps2[rowg + r][h] = s2r[r]; }
    }
    __syncthreads();
    if (h == 0 && lane < QB) {
        float a = 0.f, c = 0.f;
#pragma unroll
        for (int w = 0; w < NHEAD; ++w) { a += ps1[lane][w]; c += ps2[lane][w]; }
        float mean = a * (1.f / EMB);
        float var = c * (1.f / EMB) - mean * mean;
        mu[lane] = mean;
        rs[lane] = rsqrtf(var + LN_EPS);
    }
    __syncthreads();

#pragma unroll
    for (int nj = 0; nj < 4; ++nj) {
        int col = h * HD + nj * 16 + fr;
        float g = gamma[col], be = beta[col];
#pragma unroll
        for (int r = 0; r < 4; ++r) {
            int row = q0 + rowg + r;
            out[((size_t)(b * SEQ + row)) * EMB + col] =
                g * (xv[nj][r] - mu[rowg + r]) * rs[rowg + r] + be;
        }
    }
}

// ---------------- launch ----------------
extern "C" void kernel_launch(void* const* d_in, const int* in_sizes, int n_in,
                              void* d_out, int out_size, void* d_ws, size_t ws_size,
                              hipStream_t stream)
{
    const float* q     = (const float*)d_in[0];
    const float* k     = (const float*)d_in[1];
    const float* v     = (const float*)d_in[2];
    const float* amask = (const float*)d_in[3];
    const float* Wq    = (const float*)d_in[4];
    const float* bq    = (const float*)d_in[5];
    const float* Wk    = (const float*)d_in[6];
    const float* bk    = (const float*)d_in[7];
    const float* Wv    = (const float*)d_in[8];
    const float* bv    = (const float*)d_in[9];
    const float* ww    = (const float*)d_in[10];
    const float* gamma = (const float*)d_in[11];
    const float* beta  = (const float*)d_in[12];
    float* out = (float*)d_out;

    char* ws = (char*)d_ws;
    u16*   Abf  = (u16*)(ws);                    // 18,874,368 B
    u16*   Wbf  = (u16*)(ws + 18874368);         //  3,538,944 B
    u16*   Qbf  = (u16*)(ws + 22413312);         //  6,291,456 B
    u16*   Kbf  = (u16*)(ws + 28704768);         //  6,291,456 B
    u16*   Vbf  = (u16*)(ws + 34996224);         //  6,291,456 B
    float* Vsum = (float*)(ws + 41287680);       //     12,288 B

    hipLaunchKernelGGL(cast_all, dim3(10944), dim3(256), 0, stream,
                       q, k, v, Wq, Wk, Wv, Abf, Wbf);
    hipLaunchKernelGGL(gemm_qkv, dim3(GN / 128, MROWS / 64, 3), dim3(256), 0, stream,
                       Abf, Wbf, bq, bk, bv, Qbf, Kbf, Vbf);
    hipLaunchKernelGGL(vsum_kernel, dim3(EMB / 64, NBAT), dim3(256), 0, stream,
                       Vbf, Vsum);
    hipLaunchKernelGGL(attn_ln, dim3(SEQ / QB, NBAT), dim3(768), 0, stream,
                       Qbf, Kbf, Vbf, Vsum, amask, ww, gamma, beta, out);
}